// Round 1
// baseline (1052.832 us; speedup 1.0000x reference)
//
#include <hip/hip_runtime.h>
#include <math.h>

#define S_DIM 128
#define N_RES 256
#define DMSA  256
#define D_HID 32
#define D_PAIR 128

// ws layout (bytes)
#define OFF_NORM  0ull                       // 256*256*4      = 262144
#define OFF_AT    262144ull                  // 256*32*128*4   = 4194304
#define OFF_BT    4456448ull                 // same
#define OFF_OUTER 8650752ull                 // CI*256*1024*4

// ---------------------------------------------------------------- norm matrix
__global__ __launch_bounds__(256) void k_norm(const float* __restrict__ mask,
                                              float* __restrict__ normw) {
    int i = blockIdx.x, j = threadIdx.x;
    float acc = 0.f;
    for (int s = 0; s < S_DIM; ++s)
        acc += mask[s * N_RES + i] * mask[s * N_RES + j];
    normw[i * N_RES + j] = acc * (1.0f / 256.0f);
}

// ------------------------------------------------- LN + w1/w2 projections
// block handles 4 consecutive (s,n) rows; outputs aT[n][c][s], bT[n][e][s]
__global__ __launch_bounds__(256) void k1_lnproj(
    const float* __restrict__ m, const float* __restrict__ mask,
    const float* __restrict__ ln_w, const float* __restrict__ ln_b,
    const float* __restrict__ w1, const float* __restrict__ b1,
    const float* __restrict__ w2, const float* __restrict__ b2,
    float* __restrict__ aT, float* __restrict__ bT) {
    __shared__ float xs[4][DMSA];
    __shared__ float red[4][4][2];
    __shared__ float pacc[4][64][5];   // pad 5 to break bank conflicts
    int t = threadIdx.x;
    int r0 = blockIdx.x * 4;

    float v[4], s1[4], s2[4];
#pragma unroll
    for (int r = 0; r < 4; ++r) {
        v[r] = m[(size_t)(r0 + r) * DMSA + t];
        s1[r] = v[r]; s2[r] = v[r] * v[r];
    }
#pragma unroll
    for (int off = 32; off > 0; off >>= 1) {
#pragma unroll
        for (int r = 0; r < 4; ++r) {
            s1[r] += __shfl_down(s1[r], off, 64);
            s2[r] += __shfl_down(s2[r], off, 64);
        }
    }
    int wave = t >> 6;
    if ((t & 63) == 0) {
#pragma unroll
        for (int r = 0; r < 4; ++r) { red[wave][r][0] = s1[r]; red[wave][r][1] = s2[r]; }
    }
    __syncthreads();
    float lw = ln_w[t], lb = ln_b[t];
#pragma unroll
    for (int r = 0; r < 4; ++r) {
        float sum = red[0][r][0] + red[1][r][0] + red[2][r][0] + red[3][r][0];
        float sq  = red[0][r][1] + red[1][r][1] + red[2][r][1] + red[3][r][1];
        float mu  = sum * (1.0f / DMSA);
        float var = sq * (1.0f / DMSA) - mu * mu;
        float rstd = rsqrtf(var + 1e-5f);
        xs[r][t] = (v[r] - mu) * rstd * lw + lb;
    }
    __syncthreads();

    int o = t & 63, part = t >> 6;
    const float* wrow = (o < D_HID) ? (w1 + o * DMSA) : (w2 + (o - D_HID) * DMSA);
    float a0 = 0.f, a1 = 0.f, a2 = 0.f, a3 = 0.f;
    int d0 = part * 64;
#pragma unroll 4
    for (int d = 0; d < 64; ++d) {
        float wd = wrow[d0 + d];
        a0 += xs[0][d0 + d] * wd;
        a1 += xs[1][d0 + d] * wd;
        a2 += xs[2][d0 + d] * wd;
        a3 += xs[3][d0 + d] * wd;
    }
    pacc[part][o][0] = a0; pacc[part][o][1] = a1;
    pacc[part][o][2] = a2; pacc[part][o][3] = a3;
    __syncthreads();

    int o2 = t >> 2, r2 = t & 3;
    float sum = pacc[0][o2][r2] + pacc[1][o2][r2] + pacc[2][o2][r2] + pacc[3][o2][r2];
    int row = r0 + r2;
    int s = row >> 8, n = row & 255;
    float mk = mask[s * N_RES + n] * 0.0625f;   // 256^-0.5
    float bias = (o2 < D_HID) ? b1[o2] : b2[o2 - D_HID];
    float val = (sum + bias) * mk;
    if (o2 < D_HID) aT[((size_t)n * D_HID + o2) * S_DIM + s] = val;
    else            bT[((size_t)n * D_HID + (o2 - D_HID)) * S_DIM + s] = val;
}

// --------------------------------------------- GEMM1: outer[(i,c),(j,e)] over s
// A = aT [8192 x 128], B = bT [8192 x 128], both K-contiguous. 64x64 tile.
__global__ __launch_bounds__(256) void k2_gemm1(const float* __restrict__ aT,
                                                const float* __restrict__ bT,
                                                float* __restrict__ outer, int i0) {
    __shared__ __align__(16) float As[32][68];
    __shared__ __align__(16) float Bs[32][68];
    int t = threadIdx.x;
    int tx = t & 15, ty = t >> 4;
    int jt = blockIdx.x, bi = blockIdx.y;
    const float* Ab = aT + ((size_t)i0 * D_HID + (size_t)bi * 64) * S_DIM;
    const float* Bb = bT + (size_t)jt * 64 * S_DIM;
    float acc[4][4] = {};
    int mr = t >> 3, k4 = (t & 7) * 4;

    for (int k0 = 0; k0 < S_DIM; k0 += 32) {
        __syncthreads();
#pragma unroll
        for (int h = 0; h < 2; ++h) {
            int mm = h * 32 + mr;
            float4 va = *(const float4*)(Ab + (size_t)mm * S_DIM + k0 + k4);
            As[k4 + 0][mm] = va.x; As[k4 + 1][mm] = va.y;
            As[k4 + 2][mm] = va.z; As[k4 + 3][mm] = va.w;
            float4 vb = *(const float4*)(Bb + (size_t)mm * S_DIM + k0 + k4);
            Bs[k4 + 0][mm] = vb.x; Bs[k4 + 1][mm] = vb.y;
            Bs[k4 + 2][mm] = vb.z; Bs[k4 + 3][mm] = vb.w;
        }
        __syncthreads();
#pragma unroll
        for (int k = 0; k < 32; ++k) {
            float4 a4 = *(const float4*)&As[k][ty * 4];
            float4 b4 = *(const float4*)&Bs[k][tx * 4];
            float av[4] = {a4.x, a4.y, a4.z, a4.w};
            float bv[4] = {b4.x, b4.y, b4.z, b4.w};
#pragma unroll
            for (int i = 0; i < 4; ++i)
#pragma unroll
                for (int j = 0; j < 4; ++j)
                    acc[i][j] += av[i] * bv[j];
        }
    }
#pragma unroll
    for (int i = 0; i < 4; ++i) {
        int mrow = bi * 64 + ty * 4 + i;
        int il = mrow >> 5, c = mrow & 31;
#pragma unroll
        for (int j = 0; j < 4; ++j) {
            int ncol = jt * 64 + tx * 4 + j;
            int jj = ncol >> 5, e = ncol & 31;
            outer[(size_t)il * (256 * 1024) + (size_t)jj * 1024 + c * 32 + e] = acc[i][j];
        }
    }
}

// --------------------------------- GEMM2: z[pair,p] = outer[pair,:]·w_out[p,:]
// 64 rows x 128 cols tile, K=1024 in chunks of 32
__global__ __launch_bounds__(256) void k2_gemm2(const float* __restrict__ outer,
                                                const float* __restrict__ w_out,
                                                const float* __restrict__ b_out,
                                                float* __restrict__ z, int i0) {
    __shared__ float As2[64][33];
    __shared__ float Bs2[128][33];
    int t = threadIdx.x;
    int tx = t & 15, ty = t >> 4;
    int rb = blockIdx.x * 64;
    float acc[4][8] = {};
    int r = t >> 3, k4 = (t & 7) * 4;

    for (int k0 = 0; k0 < 1024; k0 += 32) {
        __syncthreads();
#pragma unroll
        for (int h = 0; h < 2; ++h) {
            int rr = h * 32 + r;
            float4 v = *(const float4*)(outer + (size_t)(rb + rr) * 1024 + k0 + k4);
            As2[rr][k4 + 0] = v.x; As2[rr][k4 + 1] = v.y;
            As2[rr][k4 + 2] = v.z; As2[rr][k4 + 3] = v.w;
        }
#pragma unroll
        for (int h = 0; h < 4; ++h) {
            int rr = h * 32 + r;
            float4 v = *(const float4*)(w_out + (size_t)rr * 1024 + k0 + k4);
            Bs2[rr][k4 + 0] = v.x; Bs2[rr][k4 + 1] = v.y;
            Bs2[rr][k4 + 2] = v.z; Bs2[rr][k4 + 3] = v.w;
        }
        __syncthreads();
#pragma unroll
        for (int k = 0; k < 32; ++k) {
            float a_[4], b_[8];
#pragma unroll
            for (int i = 0; i < 4; ++i) a_[i] = As2[ty * 4 + i][k];
#pragma unroll
            for (int j = 0; j < 8; ++j) b_[j] = Bs2[tx + j * 16][k];
#pragma unroll
            for (int i = 0; i < 4; ++i)
#pragma unroll
                for (int j = 0; j < 8; ++j)
                    acc[i][j] += a_[i] * b_[j];
        }
    }
#pragma unroll
    for (int i = 0; i < 4; ++i) {
        size_t ob = ((size_t)i0 * 256 + rb + ty * 4 + i) * D_PAIR;
#pragma unroll
        for (int j = 0; j < 8; ++j) {
            int p = tx + j * 16;
            z[ob + p] = acc[i][j] + b_out[p];
        }
    }
}

// ------------------- epilogue: /(eps+norm), gelu, LN(128), x@wz^T + bz (in place)
__global__ __launch_bounds__(256) void k3_epilogue(float* __restrict__ z,
    const float* __restrict__ normw,
    const float* __restrict__ ln_ow, const float* __restrict__ ln_ob,
    const float* __restrict__ wzm, const float* __restrict__ bz) {
    __shared__ float zall[16][128];
    __shared__ float red[2][8];
    int t = threadIdx.x;
    int rr = t >> 7, p = t & 127;
    int base = blockIdx.x * 16;
    float lw = ln_ow[p], lb = ln_ob[p];

    for (int it = 0; it < 8; ++it) {
        int row = base + it * 2 + rr;
        float zv = z[(size_t)row * D_PAIR + p];
        zv = zv / (1e-3f + normw[row]);
        zv = 0.5f * zv * (1.0f + erff(zv * 0.70710678118654752f));
        float s1 = zv, s2 = zv * zv;
#pragma unroll
        for (int off = 32; off > 0; off >>= 1) {
            s1 += __shfl_down(s1, off, 64);
            s2 += __shfl_down(s2, off, 64);
        }
        int wir = (t >> 6) & 1;
        float* rs = red[it & 1];
        if ((t & 63) == 0) { rs[rr * 4 + wir * 2 + 0] = s1; rs[rr * 4 + wir * 2 + 1] = s2; }
        __syncthreads();
        float sum = rs[rr * 4 + 0] + rs[rr * 4 + 2];
        float sq  = rs[rr * 4 + 1] + rs[rr * 4 + 3];
        float mu  = sum * (1.0f / D_PAIR);
        float rstd = rsqrtf(sq * (1.0f / D_PAIR) - mu * mu + 1e-5f);
        zall[it * 2 + rr][p] = (zv - mu) * rstd * lw + lb;
    }
    __syncthreads();

    int rg = t >> 6, lane = t & 63;
    float acc0[4], acc1[4];
#pragma unroll
    for (int i = 0; i < 4; ++i) { acc0[i] = bz[lane]; acc1[i] = bz[lane + 64]; }
    const float* wr0 = wzm + lane * 128;
    const float* wr1 = wzm + (lane + 64) * 128;
    for (int pp = 0; pp < 128; pp += 4) {
        float4 b0 = *(const float4*)(wr0 + pp);
        float4 b1 = *(const float4*)(wr1 + pp);
#pragma unroll
        for (int i = 0; i < 4; ++i) {
            float4 a4 = *(const float4*)&zall[rg * 4 + i][pp];
            acc0[i] += a4.x * b0.x + a4.y * b0.y + a4.z * b0.z + a4.w * b0.w;
            acc1[i] += a4.x * b1.x + a4.y * b1.y + a4.z * b1.z + a4.w * b1.w;
        }
    }
#pragma unroll
    for (int i = 0; i < 4; ++i) {
        int row = base + rg * 4 + i;
        z[(size_t)row * D_PAIR + lane]      = acc0[i];
        z[(size_t)row * D_PAIR + lane + 64] = acc1[i];
    }
}

extern "C" void kernel_launch(void* const* d_in, const int* in_sizes, int n_in,
                              void* d_out, int out_size, void* d_ws, size_t ws_size,
                              hipStream_t stream) {
    const float* m      = (const float*)d_in[0];
    const float* mask   = (const float*)d_in[1];
    const float* ln_w   = (const float*)d_in[2];
    const float* ln_b   = (const float*)d_in[3];
    const float* w1     = (const float*)d_in[4];
    const float* b1     = (const float*)d_in[5];
    const float* w2     = (const float*)d_in[6];
    const float* b2     = (const float*)d_in[7];
    const float* w_out  = (const float*)d_in[8];
    const float* b_out  = (const float*)d_in[9];
    const float* ln_ow  = (const float*)d_in[10];
    const float* ln_ob  = (const float*)d_in[11];
    const float* wz     = (const float*)d_in[12];
    const float* bz     = (const float*)d_in[13];
    float* out = (float*)d_out;
    char*  ws  = (char*)d_ws;

    float* normw = (float*)(ws + OFF_NORM);
    float* aT    = (float*)(ws + OFF_AT);
    float* bT    = (float*)(ws + OFF_BT);
    float* outer = (float*)(ws + OFF_OUTER);

    // pick i-chunk so scratch fits ws_size (deterministic across calls)
    int CI = 2;
    const int cands[5] = {64, 32, 16, 8, 4};
    for (int k = 0; k < 5; ++k) {
        if (ws_size >= OFF_OUTER + (size_t)cands[k] * 1048576ull) { CI = cands[k]; break; }
    }

    k_norm<<<dim3(256), dim3(256), 0, stream>>>(mask, normw);
    k1_lnproj<<<dim3(8192), dim3(256), 0, stream>>>(m, mask, ln_w, ln_b, w1, b1, w2, b2, aT, bT);
    for (int i0 = 0; i0 < 256; i0 += CI) {
        k2_gemm1<<<dim3(128, CI / 2), dim3(256), 0, stream>>>(aT, bT, outer, i0);
        k2_gemm2<<<dim3(CI * 4), dim3(256), 0, stream>>>(outer, w_out, b_out, out, i0);
    }
    k3_epilogue<<<dim3(4096), dim3(256), 0, stream>>>(out, normw, ln_ow, ln_ob, wz, bz);
}

// Round 3
// 396.773 us; speedup vs baseline: 2.6535x; 2.6535x over previous
//
#include <hip/hip_runtime.h>
#include <math.h>

#define S_DIM 128
#define N_RES 256
#define DMSA  256
#define D_HID 32
#define D_PAIR 128
#define EPSC 1e-3f

typedef __attribute__((ext_vector_type(8))) short short8;
typedef __attribute__((ext_vector_type(4))) float float4v;

static __device__ __forceinline__ unsigned short f2bf(float f) {
    union { float f; unsigned u; } x; x.f = f;
    unsigned r = x.u + 0x7FFFu + ((x.u >> 16) & 1u);
    return (unsigned short)(r >> 16);
}

static __device__ __forceinline__ float4v mfma16(short8 a, short8 b, float4v c) {
    return __builtin_amdgcn_mfma_f32_16x16x32_bf16(a, b, c, 0, 0, 0);
}

// ws layout (bytes)
#define OFF_NORM 0ull           // 256*256*4   = 262144
#define OFF_AT   262144ull      // 8192*128*2  = 2097152
#define OFF_BT   2359296ull     // 2097152
#define OFF_WOB  4456448ull     // 128*1024*2  = 262144
#define OFF_WZB  4718592ull     // 128*128*2   = 32768

// ---------------------------------------------------------------- norm matrix
__global__ __launch_bounds__(256) void k_norm(const float* __restrict__ mask,
                                              float* __restrict__ normw) {
    int i = blockIdx.x, j = threadIdx.x;
    float acc = 0.f;
    for (int s = 0; s < S_DIM; ++s)
        acc += mask[s * N_RES + i] * mask[s * N_RES + j];
    normw[i * N_RES + j] = acc * (1.0f / 256.0f);
}

// ------------------------------------------------- weight convert fp32->bf16
__global__ __launch_bounds__(256) void k_cvt(const float* __restrict__ w_out,
                                             const float* __restrict__ wz,
                                             unsigned short* __restrict__ wob,
                                             unsigned short* __restrict__ wzb) {
    int idx = blockIdx.x * 256 + threadIdx.x;
    if (idx < 131072) {
        wob[idx] = f2bf(w_out[idx]);
    } else {
        int k = idx - 131072;
        if (k < 16384) wzb[k] = f2bf(wz[k]);
    }
}

// ------------------------------------------------- LN + w1/w2 projections
// block handles 4 consecutive (s,n) rows; outputs aT[n*32+c][s], bT[n*32+e][s] (bf16)
__global__ __launch_bounds__(256) void k1_lnproj(
    const float* __restrict__ m, const float* __restrict__ mask,
    const float* __restrict__ ln_w, const float* __restrict__ ln_b,
    const float* __restrict__ w1, const float* __restrict__ b1,
    const float* __restrict__ w2, const float* __restrict__ b2,
    unsigned short* __restrict__ aT, unsigned short* __restrict__ bT) {
    __shared__ float xs[4][DMSA];
    __shared__ float red[4][4][2];
    __shared__ float pacc[4][64][5];
    int t = threadIdx.x;
    int r0 = blockIdx.x * 4;

    float v[4], s1[4], s2[4];
#pragma unroll
    for (int r = 0; r < 4; ++r) {
        v[r] = m[(size_t)(r0 + r) * DMSA + t];
        s1[r] = v[r]; s2[r] = v[r] * v[r];
    }
#pragma unroll
    for (int off = 32; off > 0; off >>= 1) {
#pragma unroll
        for (int r = 0; r < 4; ++r) {
            s1[r] += __shfl_down(s1[r], off, 64);
            s2[r] += __shfl_down(s2[r], off, 64);
        }
    }
    int wave = t >> 6;
    if ((t & 63) == 0) {
#pragma unroll
        for (int r = 0; r < 4; ++r) { red[wave][r][0] = s1[r]; red[wave][r][1] = s2[r]; }
    }
    __syncthreads();
    float lw = ln_w[t], lb = ln_b[t];
#pragma unroll
    for (int r = 0; r < 4; ++r) {
        float sum = red[0][r][0] + red[1][r][0] + red[2][r][0] + red[3][r][0];
        float sq  = red[0][r][1] + red[1][r][1] + red[2][r][1] + red[3][r][1];
        float mu  = sum * (1.0f / DMSA);
        float var = sq * (1.0f / DMSA) - mu * mu;
        float rstd = rsqrtf(var + 1e-5f);
        xs[r][t] = (v[r] - mu) * rstd * lw + lb;
    }
    __syncthreads();

    int o = t & 63, part = t >> 6;
    const float* wrow = (o < D_HID) ? (w1 + o * DMSA) : (w2 + (o - D_HID) * DMSA);
    float a0 = 0.f, a1 = 0.f, a2 = 0.f, a3 = 0.f;
    int d0 = part * 64;
#pragma unroll 4
    for (int d = 0; d < 64; ++d) {
        float wd = wrow[d0 + d];
        a0 += xs[0][d0 + d] * wd;
        a1 += xs[1][d0 + d] * wd;
        a2 += xs[2][d0 + d] * wd;
        a3 += xs[3][d0 + d] * wd;
    }
    pacc[part][o][0] = a0; pacc[part][o][1] = a1;
    pacc[part][o][2] = a2; pacc[part][o][3] = a3;
    __syncthreads();

    int o2 = t >> 2, r2 = t & 3;
    float sum = pacc[0][o2][r2] + pacc[1][o2][r2] + pacc[2][o2][r2] + pacc[3][o2][r2];
    int row = r0 + r2;
    int s = row >> 8, n = row & 255;
    float mk = mask[s * N_RES + n] * 0.0625f;   // 256^-0.5
    float bias = (o2 < D_HID) ? b1[o2] : b2[o2 - D_HID];
    float val = (sum + bias) * mk;
    if (o2 < D_HID) aT[((size_t)n * D_HID + o2) * S_DIM + s] = f2bf(val);
    else            bT[((size_t)n * D_HID + (o2 - D_HID)) * S_DIM + s] = f2bf(val);
}

// =============== fused: GEMM1 (outer) + GEMM2 (w_out) + epilogue + wz ========
// one 128x128 tile of (ic, je) per workgroup = 4x4 (i,j) pairs, K=s=128.
__global__ __launch_bounds__(256, 2) void k2_fused(
    const unsigned short* __restrict__ aT, const unsigned short* __restrict__ bT,
    const unsigned short* __restrict__ wob, const unsigned short* __restrict__ wzb,
    const float* __restrict__ b_out, const float* __restrict__ normw,
    const float* __restrict__ ln_ow, const float* __restrict__ ln_ob,
    const float* __restrict__ bz, float* __restrict__ out)
{
    __shared__ char smem[69632];
    unsigned short* As = (unsigned short*)smem;             // [128][136] bf16
    unsigned short* Bs = (unsigned short*)(smem + 34816);   // [128][136] bf16
    unsigned* oL32 = (unsigned*)smem;                       // outer: 16 pairs x 516 dwords (bf16 pairs), XOR-swizzled within pair
    float* zL = (float*)(smem + 33024);                     // [16][132] f32
    unsigned short* lnL = (unsigned short*)(smem + 41472);  // [16][136] bf16

    int t = threadIdx.x;
    int w = t >> 6, lane = t & 63;
    int g = lane >> 4, l15 = lane & 15;
    int bj = blockIdx.x, bi = blockIdx.y;

    // ---------------- stage A,B tiles (full K=128) ----------------
    const char* Ag = (const char*)(aT + (size_t)bi * 128 * 128);
    const char* Bg = (const char*)(bT + (size_t)bj * 128 * 128);
#pragma unroll
    for (int h = 0; h < 8; ++h) {
        int q = t + 256 * h;
        int row = q >> 4, c16 = q & 15;
        uint4 va = *(const uint4*)(Ag + row * 256 + c16 * 16);
        *(uint4*)(smem + row * 272 + c16 * 16) = va;
        uint4 vb = *(const uint4*)(Bg + row * 256 + c16 * 16);
        *(uint4*)(smem + 34816 + row * 272 + c16 * 16) = vb;
    }
    __syncthreads();

    // ---------------- GEMM1: 64x64 per wave, 16 frags ----------------
    int wm = w >> 1, wn = w & 1;
    float4v zf = {0.f, 0.f, 0.f, 0.f};
    float4v acc[4][4];
#pragma unroll
    for (int fm = 0; fm < 4; ++fm)
#pragma unroll
        for (int fn = 0; fn < 4; ++fn) acc[fm][fn] = zf;

#pragma unroll
    for (int kk = 0; kk < 4; ++kk) {
        short8 af[4], bf[4];
#pragma unroll
        for (int fm = 0; fm < 4; ++fm)
            af[fm] = *(const short8*)(As + (wm * 64 + fm * 16 + l15) * 136 + kk * 32 + g * 8);
#pragma unroll
        for (int fn = 0; fn < 4; ++fn)
            bf[fn] = *(const short8*)(Bs + (wn * 64 + fn * 16 + l15) * 136 + kk * 32 + g * 8);
#pragma unroll
        for (int fm = 0; fm < 4; ++fm)
#pragma unroll
            for (int fn = 0; fn < 4; ++fn)
                acc[fm][fn] = mfma16(af[fm], bf[fn], acc[fm][fn]);
    }
    __syncthreads();   // all GEMM1 LDS reads done; reuse As/Bs region for outer

    // -------- pack outer -> LDS bf16 [pair][ce] with within-pair XOR swizzle --------
    // frag C layout: row(ic_local) = (lane>>4)*4 + r, col(je_local) = l15
#pragma unroll
    for (int fm = 0; fm < 4; ++fm) {
#pragma unroll
        for (int fn = 0; fn < 4; ++fn) {
            int pair = (wm * 2 + (fm >> 1)) * 4 + wn * 2 + (fn >> 1);
            int e = (fn & 1) * 16 + l15;
#pragma unroll
            for (int r = 0; r < 4; ++r) {
                int c = (fm & 1) * 16 + g * 4 + r;
                float v = acc[fm][fn][r];
                float vn = __shfl_xor(v, 1);
                if ((l15 & 1) == 0) {
                    unsigned pk = (unsigned)f2bf(v) | ((unsigned)f2bf(vn) << 16);
                    // within-pair offset in dwords, XOR-swizzled WITHIN the pair region
                    int off = c * 16 + (e >> 1);
                    off ^= ((c >> 2) & 3) << 2;
                    oL32[pair * 516 + off] = pk;
                }
            }
        }
    }
    __syncthreads();

    // ---------------- GEMM2: z[16 pairs][128 p], K=1024 ----------------
    int p0 = w * 32;
    float4v acc2[2]; acc2[0] = zf; acc2[1] = zf;
#pragma unroll
    for (int kk = 0; kk < 32; ++kk) {
        int off = kk * 16 + g * 4;
        off ^= ((kk >> 2) & 3) << 2;
        short8 af = *(const short8*)((const char*)oL32 + ((size_t)(l15 * 516 + off)) * 4);
#pragma unroll
        for (int f = 0; f < 2; ++f) {
            short8 bf2 = *(const short8*)(wob + (size_t)(p0 + f * 16 + l15) * 1024 + kk * 32 + g * 8);
            acc2[f] = mfma16(af, bf2, acc2[f]);
        }
    }
#pragma unroll
    for (int f = 0; f < 2; ++f)
#pragma unroll
        for (int r = 0; r < 4; ++r)
            zL[(g * 4 + r) * 132 + p0 + f * 16 + l15] = acc2[f][r];
    __syncthreads();

    // ---------------- epilogue: +b_out, /(eps+norm), gelu, LN ----------------
    {
        int pair = w * 4 + g;                    // wave w handles pairs w*4..w*4+3
        int iG = bi * 4 + w, jG = bj * 4 + g;
        float nw = normw[iG * 256 + jG];
        float inv = 1.0f / (EPSC + nw);
        float4v z0 = *(const float4v*)(zL + pair * 132 + l15 * 8);
        float4v z1 = *(const float4v*)(zL + pair * 132 + l15 * 8 + 4);
        float vals[8];
        float sum = 0.f, sq = 0.f;
#pragma unroll
        for (int e2 = 0; e2 < 8; ++e2) {
            int p = l15 * 8 + e2;
            float v = ((e2 < 4) ? z0[e2] : z1[e2 - 4]) + b_out[p];
            v *= inv;
            v = 0.5f * v * (1.0f + erff(v * 0.70710678118654752f));
            vals[e2] = v; sum += v; sq += v * v;
        }
#pragma unroll
        for (int mm = 1; mm <= 8; mm <<= 1) {
            sum += __shfl_xor(sum, mm);
            sq  += __shfl_xor(sq, mm);
        }
        float mu = sum * (1.0f / 128.0f);
        float var = sq * (1.0f / 128.0f) - mu * mu;
        float rstd = rsqrtf(var + 1e-5f);
        unsigned pk[4];
#pragma unroll
        for (int e2 = 0; e2 < 8; e2 += 2) {
            int p = l15 * 8 + e2;
            float o0 = (vals[e2] - mu) * rstd * ln_ow[p] + ln_ob[p];
            float o1 = (vals[e2 + 1] - mu) * rstd * ln_ow[p + 1] + ln_ob[p + 1];
            pk[e2 >> 1] = (unsigned)f2bf(o0) | ((unsigned)f2bf(o1) << 16);
        }
        uint4 upk; upk.x = pk[0]; upk.y = pk[1]; upk.z = pk[2]; upk.w = pk[3];
        *(uint4*)(lnL + pair * 136 + l15 * 8) = upk;
    }
    __syncthreads();

    // ---------------- wz matmul + bz, store ----------------
    float4v acc3[2]; acc3[0] = zf; acc3[1] = zf;
#pragma unroll
    for (int kk = 0; kk < 4; ++kk) {
        short8 af = *(const short8*)(lnL + l15 * 136 + kk * 32 + g * 8);
#pragma unroll
        for (int f = 0; f < 2; ++f) {
            short8 bf3 = *(const short8*)(wzb + (size_t)(p0 + f * 16 + l15) * 128 + kk * 32 + g * 8);
            acc3[f] = mfma16(af, bf3, acc3[f]);
        }
    }
#pragma unroll
    for (int f = 0; f < 2; ++f) {
        int q = p0 + f * 16 + l15;
        float bzq = bz[q];
#pragma unroll
        for (int r = 0; r < 4; ++r) {
            int row = (bi * 4 + g) * 256 + bj * 4 + r;   // pair = g*4+r -> i_loc=g, j_loc=r
            out[(size_t)row * 128 + q] = acc3[f][r] + bzq;
        }
    }
}

extern "C" void kernel_launch(void* const* d_in, const int* in_sizes, int n_in,
                              void* d_out, int out_size, void* d_ws, size_t ws_size,
                              hipStream_t stream) {
    const float* m      = (const float*)d_in[0];
    const float* mask   = (const float*)d_in[1];
    const float* ln_w   = (const float*)d_in[2];
    const float* ln_b   = (const float*)d_in[3];
    const float* w1     = (const float*)d_in[4];
    const float* b1     = (const float*)d_in[5];
    const float* w2     = (const float*)d_in[6];
    const float* b2     = (const float*)d_in[7];
    const float* w_out  = (const float*)d_in[8];
    const float* b_out  = (const float*)d_in[9];
    const float* ln_ow  = (const float*)d_in[10];
    const float* ln_ob  = (const float*)d_in[11];
    const float* wz     = (const float*)d_in[12];
    const float* bz     = (const float*)d_in[13];
    float* out = (float*)d_out;
    char*  ws  = (char*)d_ws;

    float* normw          = (float*)(ws + OFF_NORM);
    unsigned short* aTb   = (unsigned short*)(ws + OFF_AT);
    unsigned short* bTb   = (unsigned short*)(ws + OFF_BT);
    unsigned short* wob   = (unsigned short*)(ws + OFF_WOB);
    unsigned short* wzb   = (unsigned short*)(ws + OFF_WZB);

    k_norm<<<dim3(256), dim3(256), 0, stream>>>(mask, normw);
    k_cvt<<<dim3(576), dim3(256), 0, stream>>>(w_out, wz, wob, wzb);
    k1_lnproj<<<dim3(8192), dim3(256), 0, stream>>>(m, mask, ln_w, ln_b, w1, b1, w2, b2, aTb, bTb);
    k2_fused<<<dim3(64, 64), dim3(256), 0, stream>>>(aTb, bTb, wob, wzb, b_out, normw,
                                                     ln_ow, ln_ob, bz, out);
}

// Round 4
// 192.764 us; speedup vs baseline: 5.4618x; 2.0583x over previous
//
#include <hip/hip_runtime.h>
#include <math.h>

#define EPSC 1e-3f

typedef __attribute__((ext_vector_type(8))) short short8;
typedef __attribute__((ext_vector_type(4))) float float4v;

static __device__ __forceinline__ unsigned short f2bf(float f) {
    union { float f; unsigned u; } x; x.f = f;
    unsigned r = x.u + 0x7FFFu + ((x.u >> 16) & 1u);
    return (unsigned short)(r >> 16);
}

static __device__ __forceinline__ float4v mfma16(short8 a, short8 b, float4v c) {
    return __builtin_amdgcn_mfma_f32_16x16x32_bf16(a, b, c, 0, 0, 0);
}

// ws layout (bytes)
#define OFF_NORM 0ull           // 256*256*4   = 262144
#define OFF_AT   262144ull      // 8192*128*2  = 2097152
#define OFF_BT   2359296ull     // 2097152
#define OFF_WOF  4456448ull     // 128*1024*2  = 262144 (frag-linear)
#define OFF_WZF  4718592ull     // 128*128*2   = 32768  (frag-linear)
#define OFF_W12  4751360ull     // 64*256*2    = 32768

// ---------------------------------------------------------------- norm matrix
__global__ __launch_bounds__(256) void k_norm(const float* __restrict__ mask,
                                              float* __restrict__ normw) {
    int i = blockIdx.x, j = threadIdx.x;
    float acc = 0.f;
#pragma unroll 8
    for (int s = 0; s < 128; ++s)
        acc += mask[s * 256 + i] * mask[s * 256 + j];
    normw[i * 256 + j] = acc * (1.0f / 256.0f);
}

// ---------------- weight convert fp32->bf16 (wob/wz into frag-linear layout)
__global__ __launch_bounds__(256) void k_cvt(const float* __restrict__ w_out,
                                             const float* __restrict__ wz,
                                             const float* __restrict__ w1,
                                             const float* __restrict__ w2,
                                             unsigned short* __restrict__ wobF,
                                             unsigned short* __restrict__ wzF,
                                             unsigned short* __restrict__ w12b) {
    int idx = blockIdx.x * 256 + threadIdx.x;
    if (idx < 131072) {
        int j = idx & 7, lane = (idx >> 3) & 63, f = (idx >> 9) & 1;
        int kk = (idx >> 10) & 31, pw = idx >> 15;
        int p = pw * 32 + f * 16 + (lane & 15);
        int k = kk * 32 + (lane >> 4) * 8 + j;
        wobF[idx] = f2bf(w_out[p * 1024 + k]);
    } else if (idx < 147456) {
        int q = idx - 131072;
        int j = q & 7, lane = (q >> 3) & 63, f = (q >> 9) & 1;
        int kk = (q >> 10) & 3, pw = q >> 12;
        int p = pw * 32 + f * 16 + (lane & 15);
        int k = kk * 32 + (lane >> 4) * 8 + j;
        wzF[q] = f2bf(wz[p * 128 + k]);
    } else if (idx < 163840) {
        int q = idx - 147456;   // h*256 + d
        w12b[q] = f2bf(q < 8192 ? w1[q] : w2[q - 8192]);
    }
}

// ------------------- LN + projections via MFMA; outputs aT/bT [n*32+c][s] bf16
// block: 8 n x 8 s = 64 rows; grid 512 (32 n-tiles x 16 s-tiles)
__global__ __launch_bounds__(256) void k1_lnproj(
    const float* __restrict__ m, const float* __restrict__ mask,
    const float* __restrict__ ln_w, const float* __restrict__ ln_b,
    const float* __restrict__ b1, const float* __restrict__ b2,
    const unsigned short* __restrict__ w12b,
    unsigned short* __restrict__ aT, unsigned short* __restrict__ bT)
{
    __shared__ unsigned short xs[64 * 272];   // 34816 B
    __shared__ unsigned short w12[64 * 272];  // 34816 B
    __shared__ unsigned short tr[64 * 76];    // 9728 B
    __shared__ float mkl[64];
    __shared__ float b12[64];
    int t = threadIdx.x;
    int w = t >> 6, lane = t & 63;
    int g = lane >> 4, l15 = lane & 15;
    int n0 = (blockIdx.x & 31) * 8, s0 = (blockIdx.x >> 5) * 8;

    // stage w12 (bf16 [64][256]) -> LDS
#pragma unroll
    for (int it = 0; it < 8; ++it) {
        int q = t + it * 256;
        int row = q >> 5, c = q & 31;
        *(uint4*)(w12 + row * 272 + c * 8) = *(const uint4*)(w12b + row * 256 + c * 8);
    }
    if (t < 64) {
        b12[t] = (t < 32) ? b1[t] : b2[t - 32];
        mkl[t] = mask[(s0 + (t >> 3)) * 256 + n0 + (t & 7)] * 0.0625f;
    }

    float4 lwv = *(const float4*)(ln_w + lane * 4);
    float4 lbv = *(const float4*)(ln_b + lane * 4);

    // LN: wave w handles rows w*16 .. w*16+15 (row r = s_l*8 + n_l)
    for (int i = 0; i < 16; ++i) {
        int r = w * 16 + i;
        size_t gr = (size_t)(s0 + (r >> 3)) * 256 + n0 + (r & 7);
        float4 v = *(const float4*)(m + gr * 256 + lane * 4);
        float sum = v.x + v.y + v.z + v.w;
        float sq = v.x*v.x + v.y*v.y + v.z*v.z + v.w*v.w;
#pragma unroll
        for (int off = 32; off > 0; off >>= 1) {
            sum += __shfl_xor(sum, off, 64);
            sq  += __shfl_xor(sq, off, 64);
        }
        float mu = sum * (1.f / 256.f);
        float rstd = rsqrtf(sq * (1.f / 256.f) - mu * mu + 1e-5f);
        uint2 u;
        u.x = (unsigned)f2bf((v.x - mu) * rstd * lwv.x + lbv.x)
            | ((unsigned)f2bf((v.y - mu) * rstd * lwv.y + lbv.y) << 16);
        u.y = (unsigned)f2bf((v.z - mu) * rstd * lwv.z + lbv.z)
            | ((unsigned)f2bf((v.w - mu) * rstd * lwv.w + lbv.w) << 16);
        *(uint2*)(xs + r * 272 + lane * 4) = u;
    }
    __syncthreads();

    // MFMA: wave w -> rows [w*16, w*16+16) x 64 h
    float4v zf = {0.f, 0.f, 0.f, 0.f};
    float4v acc[4]; acc[0] = zf; acc[1] = zf; acc[2] = zf; acc[3] = zf;
#pragma unroll
    for (int kk = 0; kk < 8; ++kk) {
        short8 af = *(const short8*)(xs + (w * 16 + l15) * 272 + kk * 32 + g * 8);
#pragma unroll
        for (int ht = 0; ht < 4; ++ht) {
            short8 bfr = *(const short8*)(w12 + (ht * 16 + l15) * 272 + kk * 32 + g * 8);
            acc[ht] = mfma16(af, bfr, acc[ht]);
        }
    }
    // epilogue: (val + bias)*mk, write bf16 to tr[h][r]
#pragma unroll
    for (int ht = 0; ht < 4; ++ht) {
        int h = ht * 16 + l15;
        float bias = b12[h];
        int rbase = w * 16 + g * 4;
        unsigned short pk[4];
#pragma unroll
        for (int ri = 0; ri < 4; ++ri)
            pk[ri] = f2bf((acc[ht][ri] + bias) * mkl[rbase + ri]);
        uint2 u;
        u.x = (unsigned)pk[0] | ((unsigned)pk[1] << 16);
        u.y = (unsigned)pk[2] | ((unsigned)pk[3] << 16);
        *(uint2*)(tr + h * 76 + rbase) = u;
    }
    __syncthreads();

    // gather 8-s runs, coalesced 16B stores
#pragma unroll
    for (int it = 0; it < 2; ++it) {
        int q = t + it * 256;       // 512 runs: h = q>>3, n_l = q&7
        int h = q >> 3, n_l = q & 7;
        unsigned short vv[8];
#pragma unroll
        for (int s_l = 0; s_l < 8; ++s_l)
            vv[s_l] = tr[h * 76 + s_l * 8 + n_l];
        uint4 u;
        u.x = (unsigned)vv[0] | ((unsigned)vv[1] << 16);
        u.y = (unsigned)vv[2] | ((unsigned)vv[3] << 16);
        u.z = (unsigned)vv[4] | ((unsigned)vv[5] << 16);
        u.w = (unsigned)vv[6] | ((unsigned)vv[7] << 16);
        int c = h & 31;
        unsigned short* dst = ((h < 32) ? aT : bT) + ((size_t)(n0 + n_l) * 32 + c) * 128 + s0;
        *(uint4*)dst = u;
    }
}

// =============== fused: GEMM1 (outer) + GEMM2 (w_out) + epilogue + wz ========
__global__ __launch_bounds__(256, 3) void k2_fused(
    const unsigned short* __restrict__ aT, const unsigned short* __restrict__ bT,
    const unsigned short* __restrict__ wobF, const unsigned short* __restrict__ wzF,
    const float* __restrict__ b_out, const float* __restrict__ normw,
    const float* __restrict__ ln_ow, const float* __restrict__ ln_ob,
    const float* __restrict__ bz, float* __restrict__ out)
{
    __shared__ char smem[49664];
    unsigned short* As = (unsigned short*)smem;               // [128][72]
    unsigned short* Bs = (unsigned short*)(smem + 18432);     // [128][72]
    unsigned* oL32 = (unsigned*)smem;                         // 16 pairs x 520 dwords
    float* zL = (float*)(smem + 36864);                       // [16][132] f32
    unsigned short* lnL = (unsigned short*)(smem + 45312);    // [16][136] bf16

    int t = threadIdx.x;
    int w = t >> 6, lane = t & 63;
    int g = lane >> 4, l15 = lane & 15;
    int bj = blockIdx.x, bi = blockIdx.y;
    int wm = w >> 1, wn = w & 1;

    const unsigned short* Ag = aT + (size_t)bi * 128 * 128;
    const unsigned short* Bg = bT + (size_t)bj * 128 * 128;

    float4v zf = {0.f, 0.f, 0.f, 0.f};
    float4v acc[4][4];
#pragma unroll
    for (int fm = 0; fm < 4; ++fm)
#pragma unroll
        for (int fn = 0; fn < 4; ++fn) acc[fm][fn] = zf;

    // ---------------- GEMM1 with K staged in halves ----------------
    for (int p = 0; p < 2; ++p) {
        if (p) __syncthreads();
#pragma unroll
        for (int h2 = 0; h2 < 4; ++h2) {
            int q = t + h2 * 256;
            int row = q >> 3, c8 = q & 7;
            *(uint4*)(As + row * 72 + c8 * 8) = *(const uint4*)(Ag + row * 128 + p * 64 + c8 * 8);
            *(uint4*)(Bs + row * 72 + c8 * 8) = *(const uint4*)(Bg + row * 128 + p * 64 + c8 * 8);
        }
        __syncthreads();
#pragma unroll
        for (int kk2 = 0; kk2 < 2; ++kk2) {
            short8 af[4], bf[4];
#pragma unroll
            for (int fm = 0; fm < 4; ++fm)
                af[fm] = *(const short8*)(As + (wm * 64 + fm * 16 + l15) * 72 + kk2 * 32 + g * 8);
#pragma unroll
            for (int fn = 0; fn < 4; ++fn)
                bf[fn] = *(const short8*)(Bs + (wn * 64 + fn * 16 + l15) * 72 + kk2 * 32 + g * 8);
#pragma unroll
            for (int fm = 0; fm < 4; ++fm)
#pragma unroll
                for (int fn = 0; fn < 4; ++fn)   // swapped: D rows = je, cols = ic
                    acc[fm][fn] = mfma16(bf[fn], af[fm], acc[fm][fn]);
        }
    }
    __syncthreads();

    // -------- pack outer -> LDS bf16, in-lane pairs (no shuffles) --------
    // lane holds c = (fm&1)*16 + l15 (col), e = (fn&1)*16 + g*4 + ri (rows)
#pragma unroll
    for (int fm = 0; fm < 4; ++fm) {
#pragma unroll
        for (int fn = 0; fn < 4; ++fn) {
            int pair = (wm * 2 + (fm >> 1)) * 4 + wn * 2 + (fn >> 1);
            int c = (fm & 1) * 16 + l15;
            int sw = ((c >> 2) & 3) << 2;
            int off = ((fn & 1) * 8 + 2 * g) ^ sw;
            float4v a4 = acc[fm][fn];
            uint2 u;
            u.x = (unsigned)f2bf(a4[0]) | ((unsigned)f2bf(a4[1]) << 16);
            u.y = (unsigned)f2bf(a4[2]) | ((unsigned)f2bf(a4[3]) << 16);
            *(uint2*)(oL32 + pair * 520 + c * 16 + off) = u;
        }
    }
    __syncthreads();

    // ---------------- GEMM2: z[16 pairs][128 p], K=1024 ----------------
    int p0 = w * 32;
    float4v acc2[2]; acc2[0] = zf; acc2[1] = zf;
#pragma unroll
    for (int kk = 0; kk < 32; ++kk) {
        int sw = ((kk >> 2) & 3) << 2;
        short8 af = *(const short8*)(oL32 + l15 * 520 + kk * 16 + ((g * 4) ^ sw));
#pragma unroll
        for (int f = 0; f < 2; ++f) {
            short8 bfw = *(const short8*)(wobF + ((size_t)((w * 32 + kk) * 2 + f) * 64 + lane) * 8);
            acc2[f] = mfma16(af, bfw, acc2[f]);
        }
    }
#pragma unroll
    for (int f = 0; f < 2; ++f)
#pragma unroll
        for (int r = 0; r < 4; ++r)
            zL[(g * 4 + r) * 132 + p0 + f * 16 + l15] = acc2[f][r];
    __syncthreads();

    // ---------------- epilogue: +b_out, /(eps+norm), gelu, LN ----------------
    {
        int pair = w * 4 + g;
        int iG = bi * 4 + w, jG = bj * 4 + g;
        float nw = normw[iG * 256 + jG];
        float inv = 1.0f / (EPSC + nw);
        float4v z0 = *(const float4v*)(zL + pair * 132 + l15 * 8);
        float4v z1 = *(const float4v*)(zL + pair * 132 + l15 * 8 + 4);
        float vals[8];
        float sum = 0.f, sq = 0.f;
#pragma unroll
        for (int e2 = 0; e2 < 8; ++e2) {
            int p = l15 * 8 + e2;
            float v = ((e2 < 4) ? z0[e2] : z1[e2 - 4]) + b_out[p];
            v *= inv;
            v = 0.5f * v * (1.0f + erff(v * 0.70710678118654752f));
            vals[e2] = v; sum += v; sq += v * v;
        }
#pragma unroll
        for (int mm = 1; mm <= 8; mm <<= 1) {
            sum += __shfl_xor(sum, mm);
            sq  += __shfl_xor(sq, mm);
        }
        float mu = sum * (1.0f / 128.0f);
        float rstd = rsqrtf(sq * (1.0f / 128.0f) - mu * mu + 1e-5f);
        unsigned pk[4];
#pragma unroll
        for (int e2 = 0; e2 < 8; e2 += 2) {
            int p = l15 * 8 + e2;
            float o0 = (vals[e2] - mu) * rstd * ln_ow[p] + ln_ob[p];
            float o1 = (vals[e2 + 1] - mu) * rstd * ln_ow[p + 1] + ln_ob[p + 1];
            pk[e2 >> 1] = (unsigned)f2bf(o0) | ((unsigned)f2bf(o1) << 16);
        }
        uint4 upk; upk.x = pk[0]; upk.y = pk[1]; upk.z = pk[2]; upk.w = pk[3];
        *(uint4*)(lnL + pair * 136 + l15 * 8) = upk;
    }
    __syncthreads();

    // ---------------- wz matmul + bz, store ----------------
    float4v acc3[2]; acc3[0] = zf; acc3[1] = zf;
#pragma unroll
    for (int kk = 0; kk < 4; ++kk) {
        short8 af = *(const short8*)(lnL + l15 * 136 + kk * 32 + g * 8);
#pragma unroll
        for (int f = 0; f < 2; ++f) {
            short8 bfw = *(const short8*)(wzF + ((size_t)((w * 4 + kk) * 2 + f) * 64 + lane) * 8);
            acc3[f] = mfma16(af, bfw, acc3[f]);
        }
    }
#pragma unroll
    for (int f = 0; f < 2; ++f) {
        int q = p0 + f * 16 + l15;
        float bzq = bz[q];
#pragma unroll
        for (int r = 0; r < 4; ++r) {
            int row = (bi * 4 + g) * 256 + bj * 4 + r;   // D row g*4+r = pair -> i=g, j=r
            out[(size_t)row * 128 + q] = acc3[f][r] + bzq;
        }
    }
}

extern "C" void kernel_launch(void* const* d_in, const int* in_sizes, int n_in,
                              void* d_out, int out_size, void* d_ws, size_t ws_size,
                              hipStream_t stream) {
    const float* m      = (const float*)d_in[0];
    const float* mask   = (const float*)d_in[1];
    const float* ln_w   = (const float*)d_in[2];
    const float* ln_b   = (const float*)d_in[3];
    const float* w1     = (const float*)d_in[4];
    const float* b1     = (const float*)d_in[5];
    const float* w2     = (const float*)d_in[6];
    const float* b2     = (const float*)d_in[7];
    const float* w_out  = (const float*)d_in[8];
    const float* b_out  = (const float*)d_in[9];
    const float* ln_ow  = (const float*)d_in[10];
    const float* ln_ob  = (const float*)d_in[11];
    const float* wz     = (const float*)d_in[12];
    const float* bz     = (const float*)d_in[13];
    float* out = (float*)d_out;
    char*  ws  = (char*)d_ws;

    float* normw          = (float*)(ws + OFF_NORM);
    unsigned short* aTb   = (unsigned short*)(ws + OFF_AT);
    unsigned short* bTb   = (unsigned short*)(ws + OFF_BT);
    unsigned short* wobF  = (unsigned short*)(ws + OFF_WOF);
    unsigned short* wzF   = (unsigned short*)(ws + OFF_WZF);
    unsigned short* w12b  = (unsigned short*)(ws + OFF_W12);

    k_norm<<<dim3(256), dim3(256), 0, stream>>>(mask, normw);
    k_cvt<<<dim3(640), dim3(256), 0, stream>>>(w_out, wz, w1, w2, wobF, wzF, w12b);
    k1_lnproj<<<dim3(512), dim3(256), 0, stream>>>(m, mask, ln_w, ln_b, b1, b2, w12b, aTb, bTb);
    k2_fused<<<dim3(64, 64), dim3(256), 0, stream>>>(aTb, bTb, wobF, wzF, b_out, normw,
                                                     ln_ow, ln_ob, bz, out);
}

// Round 5
// 184.149 us; speedup vs baseline: 5.7173x; 1.0468x over previous
//
#include <hip/hip_runtime.h>
#include <hip/hip_bf16.h>
#include <math.h>

#define EPSC 1e-3f

typedef __attribute__((ext_vector_type(8))) short short8;
typedef __attribute__((ext_vector_type(4))) float float4v;

static __device__ __forceinline__ unsigned short f2bf(float f) {
    union { float f; unsigned u; } x; x.f = f;
    unsigned r = x.u + 0x7FFFu + ((x.u >> 16) & 1u);
    return (unsigned short)(r >> 16);
}

// packed f32x2 -> bf16x2 (RNE, emits v_cvt_pk_bf16_f32)
static __device__ __forceinline__ unsigned pk_bf16(float lo, float hi) {
    union { __hip_bfloat162 h; unsigned u; } cv;
    cv.h = __float22bfloat162_rn(make_float2(lo, hi));
    return cv.u;
}

static __device__ __forceinline__ float4v mfma16(short8 a, short8 b, float4v c) {
    return __builtin_amdgcn_mfma_f32_16x16x32_bf16(a, b, c, 0, 0, 0);
}

// ws layout (bytes)
#define OFF_NORM 0ull           // 256*256*4   = 262144
#define OFF_AT   262144ull      // 8192*128*2  = 2097152
#define OFF_BT   2359296ull     // 2097152
#define OFF_WOF  4456448ull     // 128*1024*2  = 262144 (frag-linear, p-slice 16/wave)
#define OFF_WZF  4718592ull     // 128*128*2   = 32768  (frag-linear)
#define OFF_W12  4751360ull     // 64*256*2    = 32768  (frag-linear)

// ---------------------------------------------------------------- norm matrix
__global__ __launch_bounds__(256) void k_norm(const float* __restrict__ mask,
                                              float* __restrict__ normw) {
    int i = blockIdx.x, j = threadIdx.x;
    float acc = 0.f;
#pragma unroll 8
    for (int s = 0; s < 128; ++s)
        acc += mask[s * 256 + i] * mask[s * 256 + j];
    normw[i * 256 + j] = acc * (1.0f / 256.0f);
}

// ---------------- weight convert fp32->bf16, all frag-linear layouts
__global__ __launch_bounds__(256) void k_cvt(const float* __restrict__ w_out,
                                             const float* __restrict__ wz,
                                             const float* __restrict__ w1,
                                             const float* __restrict__ w2,
                                             unsigned short* __restrict__ wobF,
                                             unsigned short* __restrict__ wzF,
                                             unsigned short* __restrict__ w12F) {
    int idx = blockIdx.x * 256 + threadIdx.x;
    if (idx < 131072) {
        // wobF[((w*32+kk)*64+lane)*8+j]: p = w*16 + (lane&15), k = kk*32 + (lane>>4)*8 + j
        int j = idx & 7, lane = (idx >> 3) & 63, kk = (idx >> 9) & 31, w = idx >> 14;
        int p = w * 16 + (lane & 15);
        int k = kk * 32 + (lane >> 4) * 8 + j;
        wobF[idx] = f2bf(w_out[p * 1024 + k]);
    } else if (idx < 147456) {
        int q = idx - 131072;
        // wzF[((w*4+kk)*64+lane)*8+j]: qcol = w*16 + (lane&15), k = kk*32 + (lane>>4)*8 + j
        int j = q & 7, lane = (q >> 3) & 63, kk = (q >> 9) & 3, w = q >> 11;
        int p = w * 16 + (lane & 15);
        int k = kk * 32 + (lane >> 4) * 8 + j;
        wzF[q] = f2bf(wz[p * 128 + k]);
    } else if (idx < 163840) {
        int q = idx - 147456;
        // w12F[((kk*4+ht)*64+lane)*8+j]: h = ht*16+(lane&15), d = kk*32+(lane>>4)*8+j
        int j = q & 7, lane = (q >> 3) & 63, ht = (q >> 9) & 3, kk = q >> 11;
        int h = ht * 16 + (lane & 15);
        int d = kk * 32 + (lane >> 4) * 8 + j;
        w12F[q] = f2bf(h < 32 ? w1[h * 256 + d] : w2[(h - 32) * 256 + d]);
    }
}

// ------------------- LN + projections via MFMA; outputs aT/bT [n*32+c][s] bf16
// block: 8 n x 8 s = 64 rows; grid 512 (32 n-tiles x 16 s-tiles)
__global__ __launch_bounds__(256) void k1_lnproj(
    const float* __restrict__ m, const float* __restrict__ mask,
    const float* __restrict__ ln_w, const float* __restrict__ ln_b,
    const float* __restrict__ b1, const float* __restrict__ b2,
    const unsigned short* __restrict__ w12F,
    unsigned short* __restrict__ aT, unsigned short* __restrict__ bT)
{
    __shared__ unsigned short xs[64 * 264];   // 33792 B, stride 264 (2-way banks)
    __shared__ unsigned short tr[64 * 76];    // 9728 B
    __shared__ float mkl[64];
    __shared__ float b12[64];
    int t = threadIdx.x;
    int w = t >> 6, lane = t & 63;
    int g = lane >> 4, l15 = lane & 15;
    int n0 = (blockIdx.x & 31) * 8, s0 = (blockIdx.x >> 5) * 8;

    if (t < 64) {
        b12[t] = (t < 32) ? b1[t] : b2[t - 32];
        mkl[t] = mask[(s0 + (t >> 3)) * 256 + n0 + (t & 7)] * 0.0625f;   // 256^-0.5
    }

    float4 lwv = *(const float4*)(ln_w + lane * 4);
    float4 lbv = *(const float4*)(ln_b + lane * 4);

    // LN: wave w handles rows w*16..w*16+15 (row r = s_l*8 + n_l); own-wave xs rows
    for (int i = 0; i < 16; ++i) {
        int r = w * 16 + i;
        size_t gr = (size_t)(s0 + (r >> 3)) * 256 + n0 + (r & 7);
        float4 v = *(const float4*)(m + gr * 256 + lane * 4);
        float sum = v.x + v.y + v.z + v.w;
        float sq = v.x * v.x + v.y * v.y + v.z * v.z + v.w * v.w;
#pragma unroll
        for (int off = 32; off > 0; off >>= 1) {
            sum += __shfl_xor(sum, off, 64);
            sq  += __shfl_xor(sq, off, 64);
        }
        float mu = sum * (1.f / 256.f);
        float rstd = rsqrtf(sq * (1.f / 256.f) - mu * mu + 1e-5f);
        uint2 u;
        u.x = pk_bf16((v.x - mu) * rstd * lwv.x + lbv.x, (v.y - mu) * rstd * lwv.y + lbv.y);
        u.y = pk_bf16((v.z - mu) * rstd * lwv.z + lbv.z, (v.w - mu) * rstd * lwv.w + lbv.w);
        *(uint2*)(xs + r * 264 + lane * 4) = u;
    }
    __syncthreads();   // covers b12/mkl too

    // MFMA: wave w -> rows [w*16,w*16+16) x 64 h; B-frags streamed from L2
    float4v zf = {0.f, 0.f, 0.f, 0.f};
    float4v acc[4]; acc[0] = zf; acc[1] = zf; acc[2] = zf; acc[3] = zf;
#pragma unroll
    for (int kk = 0; kk < 8; ++kk) {
        short8 af = *(const short8*)(xs + (w * 16 + l15) * 264 + kk * 32 + g * 8);
#pragma unroll
        for (int ht = 0; ht < 4; ++ht) {
            short8 bfr = *(const short8*)(w12F + ((size_t)(kk * 4 + ht) * 64 + lane) * 8);
            acc[ht] = mfma16(af, bfr, acc[ht]);
        }
    }
    // epilogue: (val + bias)*mk, write bf16 to tr[h][r]
#pragma unroll
    for (int ht = 0; ht < 4; ++ht) {
        int h = ht * 16 + l15;
        float bias = b12[h];
        int rbase = w * 16 + g * 4;
        uint2 u;
        u.x = pk_bf16((acc[ht][0] + bias) * mkl[rbase + 0], (acc[ht][1] + bias) * mkl[rbase + 1]);
        u.y = pk_bf16((acc[ht][2] + bias) * mkl[rbase + 2], (acc[ht][3] + bias) * mkl[rbase + 3]);
        *(uint2*)(tr + h * 76 + rbase) = u;
    }
    __syncthreads();

    // gather 8-s runs, coalesced 16B stores
#pragma unroll
    for (int it = 0; it < 2; ++it) {
        int q = t + it * 256;       // h = q>>3, n_l = q&7
        int h = q >> 3, n_l = q & 7;
        unsigned short vv[8];
#pragma unroll
        for (int s_l = 0; s_l < 8; ++s_l)
            vv[s_l] = tr[h * 76 + s_l * 8 + n_l];
        uint4 u;
        u.x = (unsigned)vv[0] | ((unsigned)vv[1] << 16);
        u.y = (unsigned)vv[2] | ((unsigned)vv[3] << 16);
        u.z = (unsigned)vv[4] | ((unsigned)vv[5] << 16);
        u.w = (unsigned)vv[6] | ((unsigned)vv[7] << 16);
        unsigned short* dst = ((h < 32) ? aT : bT) + ((size_t)(n0 + n_l) * 32 + (h & 31)) * 128 + s0;
        *(uint4*)dst = u;
    }
}

// =============== fused: GEMM1 + GEMM2 (w_out) + epilogue + wz ================
// 256x256 (ic,je) tile = 8x8 (i,j) pairs per block; 512 threads; 128 KiB LDS.
__global__ __launch_bounds__(512, 2) void k2_fused(
    const unsigned short* __restrict__ aT, const unsigned short* __restrict__ bT,
    const unsigned short* __restrict__ wobF, const unsigned short* __restrict__ wzF,
    const float* __restrict__ b_out, const float* __restrict__ normw,
    const float* __restrict__ ln_ow, const float* __restrict__ ln_ob,
    const float* __restrict__ bz, float* __restrict__ out)
{
    __shared__ char smem[131072];                           // exactly 128 KiB
    unsigned short* As = (unsigned short*)smem;             // [256][72] bf16
    unsigned short* Bs = (unsigned short*)(smem + 36864);   // [256][72] bf16
    unsigned* oL = (unsigned*)smem;                         // 64 pairs x 512 dw (swizzled)
    float* zL = (float*)smem;                               // [64][132] f32 (post-GEMM2)
    unsigned short* lnL = (unsigned short*)(smem + 36864);  // [64][136] bf16

    int t = threadIdx.x;
    int w = t >> 6, lane = t & 63;
    int g = lane >> 4, l15 = lane & 15;
    int bj = blockIdx.x, bi = blockIdx.y;
    int wn = w & 1, wm = w >> 1;   // wn: je-half (128), wm: ic-quarter (64)

    const unsigned short* Ag = aT + (size_t)bi * 256 * 128;
    const unsigned short* Bg = bT + (size_t)bj * 256 * 128;

    float4v zf = {0.f, 0.f, 0.f, 0.f};
    float4v acc[4][8];
#pragma unroll
    for (int fm = 0; fm < 4; ++fm)
#pragma unroll
        for (int fn = 0; fn < 8; ++fn) acc[fm][fn] = zf;

    // ---------------- GEMM1, K staged in halves of 64 ----------------
    for (int p = 0; p < 2; ++p) {
        if (p) __syncthreads();
#pragma unroll
        for (int it = 0; it < 4; ++it) {
            int q = t + it * 512;
            int row = q >> 3, c8 = q & 7;
            *(uint4*)(As + row * 72 + c8 * 8) = *(const uint4*)(Ag + row * 128 + p * 64 + c8 * 8);
            *(uint4*)(Bs + row * 72 + c8 * 8) = *(const uint4*)(Bg + row * 128 + p * 64 + c8 * 8);
        }
        __syncthreads();
#pragma unroll
        for (int kk2 = 0; kk2 < 2; ++kk2) {
            short8 af[4], bf[8];
#pragma unroll
            for (int fm = 0; fm < 4; ++fm)
                af[fm] = *(const short8*)(As + (wm * 64 + fm * 16 + l15) * 72 + kk2 * 32 + g * 8);
#pragma unroll
            for (int fn = 0; fn < 8; ++fn)
                bf[fn] = *(const short8*)(Bs + (wn * 128 + fn * 16 + l15) * 72 + kk2 * 32 + g * 8);
#pragma unroll
            for (int fm = 0; fm < 4; ++fm)
#pragma unroll
                for (int fn = 0; fn < 8; ++fn)   // swapped: D reg-dim = je, l15-dim = ic
                    acc[fm][fn] = mfma16(bf[fn], af[fm], acc[fm][fn]);
        }
    }
    __syncthreads();   // staging dead; region becomes oL

    // -------- pack outer -> LDS bf16, swizzle: dw = pair*512 + ((c*16+o)^((pair&7)<<2))
#pragma unroll
    for (int fm = 0; fm < 4; ++fm) {
#pragma unroll
        for (int fn = 0; fn < 8; ++fn) {
            int pair = (wm * 2 + (fm >> 1)) * 8 + wn * 4 + (fn >> 1);
            int c_in = (fm & 1) * 16 + l15;
            int o = (fn & 1) * 8 + 2 * g;
            int dw = pair * 512 + ((c_in * 16 + o) ^ ((pair & 7) << 2));
            float4v a4 = acc[fm][fn];
            uint2 u;
            u.x = pk_bf16(a4[0], a4[1]);
            u.y = pk_bf16(a4[2], a4[3]);
            *(uint2*)(oL + dw) = u;
        }
    }
    __syncthreads();

    // ---------------- GEMM2: z[64 pairs][128 p], K=1024; p-slice 16 per wave ---
    float4v acc2[4]; acc2[0] = zf; acc2[1] = zf; acc2[2] = zf; acc2[3] = zf;
    const unsigned short* wbase = wobF + (size_t)w * 16384;
#pragma unroll 8
    for (int kk = 0; kk < 32; ++kk) {
        short8 bfw = *(const short8*)(wbase + (kk * 64 + lane) * 8);
#pragma unroll
        for (int fr = 0; fr < 4; ++fr) {
            int dw = (fr * 16 + l15) * 512 + ((kk * 16 + g * 4) ^ ((l15 & 7) << 2));
            short8 af2 = *(const short8*)(oL + dw);
            acc2[fr] = mfma16(af2, bfw, acc2[fr]);
        }
    }
    __syncthreads();   // all oL reads done; region becomes zL/lnL
#pragma unroll
    for (int fr = 0; fr < 4; ++fr)
#pragma unroll
        for (int r = 0; r < 4; ++r)
            zL[(fr * 16 + g * 4 + r) * 132 + w * 16 + l15] = acc2[fr][r];
    __syncthreads();

    // ---------------- epilogue: +b_out, /(eps+norm), gelu, LN(128) ----------
    {
        const float4 loA = *(const float4*)(ln_ow + l15 * 8);
        const float4 loB = *(const float4*)(ln_ow + l15 * 8 + 4);
        const float4 lbA = *(const float4*)(ln_ob + l15 * 8);
        const float4 lbB = *(const float4*)(ln_ob + l15 * 8 + 4);
        const float4 boA = *(const float4*)(b_out + l15 * 8);
        const float4 boB = *(const float4*)(b_out + l15 * 8 + 4);
        float lw8[8] = {loA.x, loA.y, loA.z, loA.w, loB.x, loB.y, loB.z, loB.w};
        float lb8[8] = {lbA.x, lbA.y, lbA.z, lbA.w, lbB.x, lbB.y, lbB.z, lbB.w};
        float bo8[8] = {boA.x, boA.y, boA.z, boA.w, boB.x, boB.y, boB.z, boB.w};
#pragma unroll
        for (int it = 0; it < 2; ++it) {
            int pair = w * 8 + it * 4 + g;
            int iG = bi * 8 + (pair >> 3), jG = bj * 8 + (pair & 7);
            float inv = 1.0f / (EPSC + normw[iG * 256 + jG]);
            float4v z0 = *(const float4v*)(zL + pair * 132 + l15 * 8);
            float4v z1 = *(const float4v*)(zL + pair * 132 + l15 * 8 + 4);
            float vals[8];
            float sum = 0.f, sq = 0.f;
#pragma unroll
            for (int e2 = 0; e2 < 8; ++e2) {
                float v = ((e2 < 4) ? z0[e2] : z1[e2 - 4]) + bo8[e2];
                v *= inv;
                v = 0.5f * v * (1.0f + erff(v * 0.70710678118654752f));
                vals[e2] = v; sum += v; sq += v * v;
            }
#pragma unroll
            for (int mm = 1; mm <= 8; mm <<= 1) {
                sum += __shfl_xor(sum, mm);
                sq  += __shfl_xor(sq, mm);
            }
            float mu = sum * (1.0f / 128.0f);
            float rstd = rsqrtf(sq * (1.0f / 128.0f) - mu * mu + 1e-5f);
            uint4 upk;
            upk.x = pk_bf16((vals[0] - mu) * rstd * lw8[0] + lb8[0],
                            (vals[1] - mu) * rstd * lw8[1] + lb8[1]);
            upk.y = pk_bf16((vals[2] - mu) * rstd * lw8[2] + lb8[2],
                            (vals[3] - mu) * rstd * lw8[3] + lb8[3]);
            upk.z = pk_bf16((vals[4] - mu) * rstd * lw8[4] + lb8[4],
                            (vals[5] - mu) * rstd * lw8[5] + lb8[5]);
            upk.w = pk_bf16((vals[6] - mu) * rstd * lw8[6] + lb8[6],
                            (vals[7] - mu) * rstd * lw8[7] + lb8[7]);
            *(uint4*)(lnL + pair * 136 + l15 * 8) = upk;
        }
    }
    __syncthreads();

    // ---------------- wz matmul + bz, store; q-slice 16 per wave ----------------
    float4v acc3[4]; acc3[0] = zf; acc3[1] = zf; acc3[2] = zf; acc3[3] = zf;
#pragma unroll
    for (int kk = 0; kk < 4; ++kk) {
        short8 bfw = *(const short8*)(wzF + ((size_t)(w * 4 + kk) * 64 + lane) * 8);
#pragma unroll
        for (int fr = 0; fr < 4; ++fr) {
            short8 af3 = *(const short8*)(lnL + (fr * 16 + l15) * 136 + kk * 32 + g * 8);
            acc3[fr] = mfma16(af3, bfw, acc3[fr]);
        }
    }
    {
        float bzq = bz[w * 16 + l15];
#pragma unroll
        for (int fr = 0; fr < 4; ++fr) {
#pragma unroll
            for (int r = 0; r < 4; ++r) {
                int pair = fr * 16 + g * 4 + r;
                int row = (bi * 8 + (pair >> 3)) * 256 + bj * 8 + (pair & 7);
                out[(size_t)row * 128 + w * 16 + l15] = acc3[fr][r] + bzq;
            }
        }
    }
}

extern "C" void kernel_launch(void* const* d_in, const int* in_sizes, int n_in,
                              void* d_out, int out_size, void* d_ws, size_t ws_size,
                              hipStream_t stream) {
    const float* m      = (const float*)d_in[0];
    const float* mask   = (const float*)d_in[1];
    const float* ln_w   = (const float*)d_in[2];
    const float* ln_b   = (const float*)d_in[3];
    const float* w1     = (const float*)d_in[4];
    const float* b1     = (const float*)d_in[5];
    const float* w2     = (const float*)d_in[6];
    const float* b2     = (const float*)d_in[7];
    const float* w_out  = (const float*)d_in[8];
    const float* b_out  = (const float*)d_in[9];
    const float* ln_ow  = (const float*)d_in[10];
    const float* ln_ob  = (const float*)d_in[11];
    const float* wz     = (const float*)d_in[12];
    const float* bz     = (const float*)d_in[13];
    float* out = (float*)d_out;
    char*  ws  = (char*)d_ws;

    float* normw          = (float*)(ws + OFF_NORM);
    unsigned short* aTb   = (unsigned short*)(ws + OFF_AT);
    unsigned short* bTb   = (unsigned short*)(ws + OFF_BT);
    unsigned short* wobF  = (unsigned short*)(ws + OFF_WOF);
    unsigned short* wzF   = (unsigned short*)(ws + OFF_WZF);
    unsigned short* w12F  = (unsigned short*)(ws + OFF_W12);

    k_norm<<<dim3(256), dim3(256), 0, stream>>>(mask, normw);
    k_cvt<<<dim3(640), dim3(256), 0, stream>>>(w_out, wz, w1, w2, wobF, wzF, w12F);
    k1_lnproj<<<dim3(512), dim3(256), 0, stream>>>(m, mask, ln_w, ln_b, b1, b2, w12F, aTb, bTb);
    k2_fused<<<dim3(32, 32), dim3(512), 0, stream>>>(aTb, bTb, wobF, wzF, b_out, normw,
                                                     ln_ow, ln_ob, bz, out);
}

// Round 6
// 166.947 us; speedup vs baseline: 6.3064x; 1.1030x over previous
//
#include <hip/hip_runtime.h>
#include <hip/hip_bf16.h>
#include <math.h>

#define EPSC 1e-3f

typedef __attribute__((ext_vector_type(8)))  short  short8;
typedef __attribute__((ext_vector_type(4)))  float  float4v;
typedef __attribute__((ext_vector_type(16))) float  float16v;

static __device__ __forceinline__ unsigned short f2bf(float f) {
    union { float f; unsigned u; } x; x.f = f;
    unsigned r = x.u + 0x7FFFu + ((x.u >> 16) & 1u);
    return (unsigned short)(r >> 16);
}
static __device__ __forceinline__ unsigned pk_bf16(float lo, float hi) {
    union { __hip_bfloat162 h; unsigned u; } cv;
    cv.h = __float22bfloat162_rn(make_float2(lo, hi));
    return cv.u;
}
static __device__ __forceinline__ float4v mfma16(short8 a, short8 b, float4v c) {
    return __builtin_amdgcn_mfma_f32_16x16x32_bf16(a, b, c, 0, 0, 0);
}
static __device__ __forceinline__ float16v mfma32(short8 a, short8 b, float16v c) {
    return __builtin_amdgcn_mfma_f32_32x32x16_bf16(a, b, c, 0, 0, 0);
}

// ws layout (bytes)
#define OFF_NORM 0ull           // 256*256*4   = 262144
#define OFF_AT   262144ull      // 8192*128*2  = 2097152
#define OFF_BT   2359296ull     // 2097152
#define OFF_WOF  4456448ull     // 128*1024*2  = 262144 (32x32 frag-linear)
#define OFF_WZF  4718592ull     // 128*128*2   = 32768  (16x16 frag-linear)
#define OFF_W12  4751360ull     // 64*256*2    = 32768  (16x16 frag-linear)

// ===================== merged pre-pass: k1 | cvt | norm ======================
// blocks [0,512): LN+proj ; [512,1152): weight cvt ; [1152,1408): norm matrix
__global__ __launch_bounds__(256) void k_pre(
    const float* __restrict__ m, const float* __restrict__ mask,
    const float* __restrict__ ln_w, const float* __restrict__ ln_b,
    const float* __restrict__ w1, const float* __restrict__ b1,
    const float* __restrict__ w2, const float* __restrict__ b2,
    const float* __restrict__ w_out, const float* __restrict__ wz,
    unsigned short* __restrict__ aT, unsigned short* __restrict__ bT,
    unsigned short* __restrict__ wobF, unsigned short* __restrict__ wzF,
    const unsigned short* __restrict__ w12F_in,   // already-written? no: see below
    unsigned short* __restrict__ w12F,
    float* __restrict__ normw)
{
    __shared__ unsigned short xs[64 * 264];   // 33792 B
    __shared__ unsigned short tr[64 * 76];    // 9728 B
    __shared__ float mkl[64];
    __shared__ float b12[64];
    int t = threadIdx.x;
    int b = blockIdx.x;

    if (b >= 1152) {           // ---------------- norm matrix ----------------
        int i = b - 1152, j = t;
        float acc = 0.f;
#pragma unroll 8
        for (int s = 0; s < 128; ++s)
            acc += mask[s * 256 + i] * mask[s * 256 + j];
        normw[i * 256 + j] = acc * (1.0f / 256.0f);
        return;
    }
    if (b >= 512) {            // ---------------- weight convert -------------
        int idx = (b - 512) * 256 + t;
        if (idx < 131072) {
            // wobF[((pw*64+k16)*64+lane)*8+j] = w_out[(pw*32+(lane&31))*1024 + k16*16 + (lane>>5)*8 + j]
            int j = idx & 7, lane = (idx >> 3) & 63, k16 = (idx >> 9) & 63, pw = idx >> 15;
            int p = pw * 32 + (lane & 31);
            int k = k16 * 16 + (lane >> 5) * 8 + j;
            wobF[idx] = f2bf(w_out[p * 1024 + k]);
        } else if (idx < 147456) {
            int q = idx - 131072;
            // wzF[((w*4+kk)*64+lane)*8+j]: p = w*16+(lane&15), k = kk*32+(lane>>4)*8+j
            int j = q & 7, lane = (q >> 3) & 63, kk = (q >> 9) & 3, w = q >> 11;
            int p = w * 16 + (lane & 15);
            int k = kk * 32 + (lane >> 4) * 8 + j;
            wzF[q] = f2bf(wz[p * 128 + k]);
        } else if (idx < 163840) {
            int q = idx - 147456;
            // w12F[((kk*4+ht)*64+lane)*8+j]: h = ht*16+(lane&15), d = kk*32+(lane>>4)*8+j
            int j = q & 7, lane = (q >> 3) & 63, ht = (q >> 9) & 3, kk = q >> 11;
            int h = ht * 16 + (lane & 15);
            int d = kk * 32 + (lane >> 4) * 8 + j;
            w12F[q] = f2bf(h < 32 ? w1[h * 256 + d] : w2[(h - 32) * 256 + d]);
        }
        return;
    }

    // ---------------- LN + projections via MFMA (blocks 0..511) ----------------
    int w = t >> 6, lane = t & 63;
    int g = lane >> 4, l15 = lane & 15;
    int n0 = (b & 31) * 8, s0 = (b >> 5) * 8;

    if (t < 64) {
        b12[t] = (t < 32) ? b1[t] : b2[t - 32];
        mkl[t] = mask[(s0 + (t >> 3)) * 256 + n0 + (t & 7)] * 0.0625f;   // 256^-0.5
    }

    float4 lwv = *(const float4*)(ln_w + lane * 4);
    float4 lbv = *(const float4*)(ln_b + lane * 4);

#pragma unroll 4
    for (int i = 0; i < 16; ++i) {
        int r = w * 16 + i;
        size_t gr = (size_t)(s0 + (r >> 3)) * 256 + n0 + (r & 7);
        float4 v = *(const float4*)(m + gr * 256 + lane * 4);
        float sum = v.x + v.y + v.z + v.w;
        float sq = v.x * v.x + v.y * v.y + v.z * v.z + v.w * v.w;
#pragma unroll
        for (int off = 32; off > 0; off >>= 1) {
            sum += __shfl_xor(sum, off, 64);
            sq  += __shfl_xor(sq, off, 64);
        }
        float mu = sum * (1.f / 256.f);
        float rstd = rsqrtf(sq * (1.f / 256.f) - mu * mu + 1e-5f);
        uint2 u;
        u.x = pk_bf16((v.x - mu) * rstd * lwv.x + lbv.x, (v.y - mu) * rstd * lwv.y + lbv.y);
        u.y = pk_bf16((v.z - mu) * rstd * lwv.z + lbv.z, (v.w - mu) * rstd * lwv.w + lbv.w);
        *(uint2*)(xs + r * 264 + lane * 4) = u;
    }
    __syncthreads();

    float4v zf4 = {0.f, 0.f, 0.f, 0.f};
    float4v acc[4]; acc[0] = zf4; acc[1] = zf4; acc[2] = zf4; acc[3] = zf4;
#pragma unroll
    for (int kk = 0; kk < 8; ++kk) {
        short8 af = *(const short8*)(xs + (w * 16 + l15) * 264 + kk * 32 + g * 8);
#pragma unroll
        for (int ht = 0; ht < 4; ++ht) {
            short8 bfr = *(const short8*)(w12F_in + ((size_t)(kk * 4 + ht) * 64 + lane) * 8);
            acc[ht] = mfma16(af, bfr, acc[ht]);
        }
    }
#pragma unroll
    for (int ht = 0; ht < 4; ++ht) {
        int h = ht * 16 + l15;
        float bias = b12[h];
        int rbase = w * 16 + g * 4;
        uint2 u;
        u.x = pk_bf16((acc[ht][0] + bias) * mkl[rbase + 0], (acc[ht][1] + bias) * mkl[rbase + 1]);
        u.y = pk_bf16((acc[ht][2] + bias) * mkl[rbase + 2], (acc[ht][3] + bias) * mkl[rbase + 3]);
        *(uint2*)(tr + h * 76 + rbase) = u;
    }
    __syncthreads();

#pragma unroll
    for (int it = 0; it < 2; ++it) {
        int q = t + it * 256;
        int h = q >> 3, n_l = q & 7;
        unsigned short vv[8];
#pragma unroll
        for (int s_l = 0; s_l < 8; ++s_l)
            vv[s_l] = tr[h * 76 + s_l * 8 + n_l];
        uint4 u;
        u.x = (unsigned)vv[0] | ((unsigned)vv[1] << 16);
        u.y = (unsigned)vv[2] | ((unsigned)vv[3] << 16);
        u.z = (unsigned)vv[4] | ((unsigned)vv[5] << 16);
        u.w = (unsigned)vv[6] | ((unsigned)vv[7] << 16);
        unsigned short* dst = ((h < 32) ? aT : bT) + ((size_t)(n0 + n_l) * 32 + (h & 31)) * 128 + s0;
        *(uint4*)dst = u;
    }
}

// =============== fused: GEMM1 + GEMM2 (w_out, 32x32) + epilogue + wz =========
// 256x256 (ic,je) tile = 8x8 (i,j) pairs per block; 512 threads; 128 KiB LDS.
__global__ __launch_bounds__(512, 2) void k2_fused(
    const unsigned short* __restrict__ aT, const unsigned short* __restrict__ bT,
    const unsigned short* __restrict__ wobF, const unsigned short* __restrict__ wzF,
    const float* __restrict__ b_out, const float* __restrict__ normw,
    const float* __restrict__ ln_ow, const float* __restrict__ ln_ob,
    const float* __restrict__ bz, float* __restrict__ out)
{
    __shared__ char smem[131072];                           // exactly 128 KiB
    unsigned* s32 = (unsigned*)smem;                        // A: dw [0,16384), B: [16384,32768)
    unsigned* oL = (unsigned*)smem;                         // 64 pairs x 512 dw, swizzled
    float* zL = (float*)smem;                               // [64][132] f32
    unsigned short* lnL = (unsigned short*)(smem + 36864);  // [64][136] bf16

    int t = threadIdx.x;
    int w = t >> 6, lane = t & 63;
    int g = lane >> 4, l15 = lane & 15;
    int bj = blockIdx.x, bi = blockIdx.y;
    int wn = w & 1, wm = w >> 1;   // wn: je-half (128), wm: ic-quarter (64)

    // ---------------- stage A,B full K=128 (swizzled write, 2-way free) -------
    {
        const uint4* Agv = (const uint4*)(aT + (size_t)bi * 256 * 128);
        const uint4* Bgv = (const uint4*)(bT + (size_t)bj * 256 * 128);
#pragma unroll
        for (int it = 0; it < 8; ++it) {
            int q = t + it * 512;                 // 0..4095
            int row = q >> 4, col4 = (q & 15) * 4;
            int dcol = col4 ^ ((row & 7) << 2);
            *(uint4*)(s32 + row * 64 + dcol) = Agv[q];
            *(uint4*)(s32 + 16384 + row * 64 + dcol) = Bgv[q];
        }
    }
    __syncthreads();

    // ---------------- GEMM1: 64(ic) x 128(je) per wave ------------------------
    float4v zf4 = {0.f, 0.f, 0.f, 0.f};
    float4v acc[4][8];
#pragma unroll
    for (int fm = 0; fm < 4; ++fm)
#pragma unroll
        for (int fn = 0; fn < 8; ++fn) acc[fm][fn] = zf4;

    {
        int sw = (l15 & 7) << 2;
#pragma unroll
        for (int kk = 0; kk < 4; ++kk) {
            int col = (kk * 16 + g * 4) ^ sw;
            short8 af[4], bf[8];
#pragma unroll
            for (int fm = 0; fm < 4; ++fm) {
                int row = wm * 64 + fm * 16 + l15;
                af[fm] = *(const short8*)((const char*)(s32 + row * 64 + col));
            }
#pragma unroll
            for (int fn = 0; fn < 8; ++fn) {
                int row = wn * 128 + fn * 16 + l15;
                bf[fn] = *(const short8*)((const char*)(s32 + 16384 + row * 64 + col));
            }
#pragma unroll
            for (int fm = 0; fm < 4; ++fm)
#pragma unroll
                for (int fn = 0; fn < 8; ++fn)   // swapped: D reg-dim = je, l15-dim = ic
                    acc[fm][fn] = mfma16(bf[fn], af[fm], acc[fm][fn]);
        }
    }
    __syncthreads();   // staging region dead; becomes oL

    // ---- pack outer -> LDS bf16; sigma(pair,off) = off ^ (((pair&7)^(off>>6))<<2)
#pragma unroll
    for (int fm = 0; fm < 4; ++fm) {
#pragma unroll
        for (int fn = 0; fn < 8; ++fn) {
            int pair = (wm * 2 + (fm >> 1)) * 8 + wn * 4 + (fn >> 1);
            int c = (fm & 1) * 16 + l15;
            int o = (fn & 1) * 8 + 2 * g;
            int off = c * 16 + o;
            int dw = pair * 512 + (off ^ ((((pair & 7) ^ (off >> 6)) & 7) << 2));
            float4v a4 = acc[fm][fn];
            uint2 u;
            u.x = pk_bf16(a4[0], a4[1]);
            u.y = pk_bf16(a4[2], a4[3]);
            *(uint2*)(oL + dw) = u;
        }
    }
    __syncthreads();

    // ---------------- GEMM2 (32x32x16): z[64 pairs][128 p], K=1024 ------------
    // wave: pw = w&3 (32 p), ph = w>>2 (32 pairs)
    {
        int pw = w & 3, ph = w >> 2;
        int l31 = lane & 31, h2 = lane >> 5;
        int pairR = ph * 32 + l31;
        int prebase = pairR * 512;
        int psw = (pairR & 7);
        float16v acc32 = {0.f};
        const unsigned short* wbase = wobF + (size_t)pw * 32768;
#pragma unroll 8
        for (int k16 = 0; k16 < 64; ++k16) {
            int off = k16 * 8 + h2 * 4;
            int dw = prebase + (off ^ (((psw ^ (off >> 6)) & 7) << 2));
            short8 a2 = *(const short8*)((const char*)(oL + dw));
            short8 b2 = *(const short8*)(wbase + ((size_t)(k16 * 64 + lane)) * 8);
            acc32 = mfma32(a2, b2, acc32);
        }
        __syncthreads();   // all oL reads done; region becomes zL
#pragma unroll
        for (int reg = 0; reg < 16; ++reg) {
            int prow = ph * 32 + (reg & 3) + 8 * (reg >> 2) + 4 * h2;
            zL[prow * 132 + pw * 32 + l31] = acc32[reg];
        }
    }
    __syncthreads();

    // ---------------- epilogue: +b_out, /(eps+norm), gelu, LN(128) ------------
    {
        const float4 loA = *(const float4*)(ln_ow + l15 * 8);
        const float4 loB = *(const float4*)(ln_ow + l15 * 8 + 4);
        const float4 lbA = *(const float4*)(ln_ob + l15 * 8);
        const float4 lbB = *(const float4*)(ln_ob + l15 * 8 + 4);
        const float4 boA = *(const float4*)(b_out + l15 * 8);
        const float4 boB = *(const float4*)(b_out + l15 * 8 + 4);
        float lw8[8] = {loA.x, loA.y, loA.z, loA.w, loB.x, loB.y, loB.z, loB.w};
        float lb8[8] = {lbA.x, lbA.y, lbA.z, lbA.w, lbB.x, lbB.y, lbB.z, lbB.w};
        float bo8[8] = {boA.x, boA.y, boA.z, boA.w, boB.x, boB.y, boB.z, boB.w};
#pragma unroll
        for (int it = 0; it < 2; ++it) {
            int pair = w * 8 + it * 4 + g;
            int iG = bi * 8 + (pair >> 3), jG = bj * 8 + (pair & 7);
            float inv = 1.0f / (EPSC + normw[iG * 256 + jG]);
            float4v z0 = *(const float4v*)(zL + pair * 132 + l15 * 8);
            float4v z1 = *(const float4v*)(zL + pair * 132 + l15 * 8 + 4);
            float vals[8];
            float sum = 0.f, sq = 0.f;
#pragma unroll
            for (int e2 = 0; e2 < 8; ++e2) {
                float v = ((e2 < 4) ? z0[e2] : z1[e2 - 4]) + bo8[e2];
                v *= inv;
                v = 0.5f * v * (1.0f + erff(v * 0.70710678118654752f));
                vals[e2] = v; sum += v; sq += v * v;
            }
#pragma unroll
            for (int mm = 1; mm <= 8; mm <<= 1) {
                sum += __shfl_xor(sum, mm);
                sq  += __shfl_xor(sq, mm);
            }
            float mu = sum * (1.0f / 128.0f);
            float rstd = rsqrtf(sq * (1.0f / 128.0f) - mu * mu + 1e-5f);
            uint4 upk;
            upk.x = pk_bf16((vals[0] - mu) * rstd * lw8[0] + lb8[0],
                            (vals[1] - mu) * rstd * lw8[1] + lb8[1]);
            upk.y = pk_bf16((vals[2] - mu) * rstd * lw8[2] + lb8[2],
                            (vals[3] - mu) * rstd * lw8[3] + lb8[3]);
            upk.z = pk_bf16((vals[4] - mu) * rstd * lw8[4] + lb8[4],
                            (vals[5] - mu) * rstd * lw8[5] + lb8[5]);
            upk.w = pk_bf16((vals[6] - mu) * rstd * lw8[6] + lb8[6],
                            (vals[7] - mu) * rstd * lw8[7] + lb8[7]);
            *(uint4*)(lnL + pair * 136 + l15 * 8) = upk;
        }
    }
    __syncthreads();

    // ---------------- wz matmul + bz, store; q-slice 16 per wave --------------
    {
        float4v acc3[4]; acc3[0] = zf4; acc3[1] = zf4; acc3[2] = zf4; acc3[3] = zf4;
#pragma unroll
        for (int kk = 0; kk < 4; ++kk) {
            short8 bfw = *(const short8*)(wzF + ((size_t)(w * 4 + kk) * 64 + lane) * 8);
#pragma unroll
            for (int fr = 0; fr < 4; ++fr) {
                short8 af3 = *(const short8*)(lnL + (fr * 16 + l15) * 136 + kk * 32 + g * 8);
                acc3[fr] = mfma16(af3, bfw, acc3[fr]);
            }
        }
        float bzq = bz[w * 16 + l15];
#pragma unroll
        for (int fr = 0; fr < 4; ++fr) {
#pragma unroll
            for (int r = 0; r < 4; ++r) {
                int pair = fr * 16 + g * 4 + r;
                int row = (bi * 8 + (pair >> 3)) * 256 + bj * 8 + (pair & 7);
                out[(size_t)row * 128 + w * 16 + l15] = acc3[fr][r] + bzq;
            }
        }
    }
}

extern "C" void kernel_launch(void* const* d_in, const int* in_sizes, int n_in,
                              void* d_out, int out_size, void* d_ws, size_t ws_size,
                              hipStream_t stream) {
    const float* m      = (const float*)d_in[0];
    const float* mask   = (const float*)d_in[1];
    const float* ln_w   = (const float*)d_in[2];
    const float* ln_b   = (const float*)d_in[3];
    const float* w1     = (const float*)d_in[4];
    const float* b1     = (const float*)d_in[5];
    const float* w2     = (const float*)d_in[6];
    const float* b2     = (const float*)d_in[7];
    const float* w_out  = (const float*)d_in[8];
    const float* b_out  = (const float*)d_in[9];
    const float* ln_ow  = (const float*)d_in[10];
    const float* ln_ob  = (const float*)d_in[11];
    const float* wz     = (const float*)d_in[12];
    const float* bz     = (const float*)d_in[13];
    float* out = (float*)d_out;
    char*  ws  = (char*)d_ws;

    float* normw          = (float*)(ws + OFF_NORM);
    unsigned short* aTb   = (unsigned short*)(ws + OFF_AT);
    unsigned short* bTb   = (unsigned short*)(ws + OFF_BT);
    unsigned short* wobF  = (unsigned short*)(ws + OFF_WOF);
    unsigned short* wzF   = (unsigned short*)(ws + OFF_WZF);
    unsigned short* w12F  = (unsigned short*)(ws + OFF_W12);

    // NOTE: k_pre's LN/proj blocks (0..511) read w12F written by k_pre's cvt
    // blocks in the SAME dispatch -> cross-block ordering is NOT guaranteed.
    // To keep correctness independent of dispatch order, convert w12 first in
    // a tiny standalone kernel launch? Instead: LN/proj blocks convert their
    // own w12F inline is wasteful; we simply keep the cvt of w12 in a separate
    // prior micro-kernel to preserve ordering.
    // k_pre0: only w12F (64 blocks). Then k_pre (everything else) can use it.
    // Implemented via the same kernel with a flag would complicate; use cvt
    // blocks in k_pre for wobF/wzF (consumed only by k2, launched after), and
    // convert w12F here in k_pre0.
    {
        // inline micro-kernel via k_pre's cvt path is not order-safe; use a
        // dedicated small launch:
        struct L {
            static __global__ void __launch_bounds__(256) cvt12(
                const float* __restrict__ w1, const float* __restrict__ w2,
                unsigned short* __restrict__ w12F) {
                int q = blockIdx.x * 256 + threadIdx.x;   // 16384
                int j = q & 7, lane = (q >> 3) & 63, ht = (q >> 9) & 3, kk = q >> 11;
                int h = ht * 16 + (lane & 15);
                int d = kk * 32 + (lane >> 4) * 8 + j;
                w12F[q] = f2bf(h < 32 ? w1[h * 256 + d] : w2[(h - 32) * 256 + d]);
            }
        };
        L::cvt12<<<dim3(64), dim3(256), 0, stream>>>(w1, w2, w12F);
    }
    k_pre<<<dim3(1408), dim3(256), 0, stream>>>(m, mask, ln_w, ln_b, w1, b1, w2, b2,
                                                w_out, wz, aTb, bTb, wobF, wzF,
                                                w12F, w12F, normw);
    k2_fused<<<dim3(32, 32), dim3(512), 0, stream>>>(aTb, bTb, wobF, wzF, b_out, normw,
                                                     ln_ow, ln_ob, bz, out);
}

// Round 7
// 166.202 us; speedup vs baseline: 6.3347x; 1.0045x over previous
//
#include <hip/hip_runtime.h>
#include <hip/hip_bf16.h>
#include <math.h>

#define EPSC 1e-3f

typedef __attribute__((ext_vector_type(8)))  short  short8;
typedef __attribute__((ext_vector_type(4)))  float  float4v;
typedef __attribute__((ext_vector_type(16))) float  float16v;

static __device__ __forceinline__ unsigned short f2bf(float f) {
    union { float f; unsigned u; } x; x.f = f;
    unsigned r = x.u + 0x7FFFu + ((x.u >> 16) & 1u);
    return (unsigned short)(r >> 16);
}
static __device__ __forceinline__ unsigned pk_bf16(float lo, float hi) {
    union { __hip_bfloat162 h; unsigned u; } cv;
    cv.h = __float22bfloat162_rn(make_float2(lo, hi));
    return cv.u;
}
static __device__ __forceinline__ float4v mfma16(short8 a, short8 b, float4v c) {
    return __builtin_amdgcn_mfma_f32_16x16x32_bf16(a, b, c, 0, 0, 0);
}
static __device__ __forceinline__ float16v mfma32(short8 a, short8 b, float16v c) {
    return __builtin_amdgcn_mfma_f32_32x32x16_bf16(a, b, c, 0, 0, 0);
}

// ws layout (bytes)
#define OFF_NORM 0ull           // 256*256*4   = 262144
#define OFF_AT   262144ull      // 32 tiles * 32768 u16 * 2 = 2097152 (tile-swizzled)
#define OFF_BT   2359296ull     // 2097152
#define OFF_WOF  4456448ull     // 128*1024*2  = 262144 (K-split frag-linear)
#define OFF_WZF  4718592ull     // 128*128*2   = 32768  (16x16 frag-linear)
#define OFF_W12  4751360ull     // 64*256*2    = 32768  (16x16 frag-linear)

// ===================== merged pre-pass: LN/proj | cvt | norm =================
// blocks [0,512): LN+proj ; [512,1152): weight cvt ; [1152,1408): norm matrix
__global__ __launch_bounds__(256) void k_pre(
    const float* __restrict__ m, const float* __restrict__ mask,
    const float* __restrict__ ln_w, const float* __restrict__ ln_b,
    const float* __restrict__ w1, const float* __restrict__ b1,
    const float* __restrict__ w2, const float* __restrict__ b2,
    const float* __restrict__ w_out, const float* __restrict__ wz,
    unsigned short* __restrict__ aT, unsigned short* __restrict__ bT,
    unsigned short* __restrict__ wobF, unsigned short* __restrict__ wzF,
    const unsigned short* __restrict__ w12F_in,
    unsigned short* __restrict__ w12F,
    float* __restrict__ normw)
{
    __shared__ unsigned short xs[64 * 266];   // 34048 B (stride 266: odd-dword)
    __shared__ unsigned short tr[64 * 76];    // 9728 B
    __shared__ float mkl[64];
    __shared__ float b12[64];
    int t = threadIdx.x;
    int b = blockIdx.x;

    if (b >= 1152) {           // ---------------- norm matrix ----------------
        int i = b - 1152, j = t;
        float acc = 0.f;
#pragma unroll 8
        for (int s = 0; s < 128; ++s)
            acc += mask[s * 256 + i] * mask[s * 256 + j];
        normw[i * 256 + j] = acc * (1.0f / 256.0f);
        return;
    }
    if (b >= 512) {            // ---------------- weight convert -------------
        int idx = (b - 512) * 256 + t;
        if (idx < 131072) {
            // wobF K-split frag-linear: slice = pw*2+kh (= wave id)
            int j = idx & 7, lane = (idx >> 3) & 63, k16 = (idx >> 9) & 31;
            int kh = (idx >> 14) & 1, pw = (idx >> 15) & 3;
            int p = pw * 32 + (lane & 31);
            int k = kh * 512 + k16 * 16 + (lane >> 5) * 8 + j;
            wobF[idx] = f2bf(w_out[p * 1024 + k]);
        } else if (idx < 147456) {
            int q = idx - 131072;
            int j = q & 7, lane = (q >> 3) & 63, kk = (q >> 9) & 3, w = q >> 11;
            int p = w * 16 + (lane & 15);
            int k = kk * 32 + (lane >> 4) * 8 + j;
            wzF[q] = f2bf(wz[p * 128 + k]);
        } else if (idx < 163840) {
            int q = idx - 147456;
            int j = q & 7, lane = (q >> 3) & 63, ht = (q >> 9) & 3, kk = q >> 11;
            int h = ht * 16 + (lane & 15);
            int d = kk * 32 + (lane >> 4) * 8 + j;
            w12F[q] = f2bf(h < 32 ? w1[h * 256 + d] : w2[(h - 32) * 256 + d]);
        }
        return;
    }

    // ---------------- LN + projections via MFMA (blocks 0..511) ----------------
    int w = t >> 6, lane = t & 63;
    int g = lane >> 4, l15 = lane & 15;
    int rr = lane >> 4, l16 = lane & 15;
    int n0 = (b & 31) * 8, s0 = (b >> 5) * 8;

    if (t < 64) {
        b12[t] = (t < 32) ? b1[t] : b2[t - 32];
        mkl[t] = mask[(s0 + (t >> 3)) * 256 + n0 + (t & 7)] * 0.0625f;   // 256^-0.5
    }

    float4 lw4[4], lb4[4];
#pragma unroll
    for (int q = 0; q < 4; ++q) {
        lw4[q] = *(const float4*)(ln_w + q * 64 + l16 * 4);
        lb4[q] = *(const float4*)(ln_b + q * 64 + l16 * 4);
    }

    // LN: 4 passes x 4 rows; 16 lanes per row (shfl depth 4 vs 6)
#pragma unroll
    for (int pass = 0; pass < 4; ++pass) {
        int r = w * 16 + pass * 4 + rr;
        const float* src = m + ((size_t)(s0 + (r >> 3)) * 256 + n0 + (r & 7)) * 256;
        float4 v[4];
#pragma unroll
        for (int q = 0; q < 4; ++q)
            v[q] = *(const float4*)(src + q * 64 + l16 * 4);
        float sum = 0.f, sq = 0.f;
#pragma unroll
        for (int q = 0; q < 4; ++q) {
            sum += v[q].x + v[q].y + v[q].z + v[q].w;
            sq  += v[q].x * v[q].x + v[q].y * v[q].y + v[q].z * v[q].z + v[q].w * v[q].w;
        }
#pragma unroll
        for (int mm = 1; mm <= 8; mm <<= 1) {   // within 16-lane row group
            sum += __shfl_xor(sum, mm);
            sq  += __shfl_xor(sq, mm);
        }
        float mu = sum * (1.f / 256.f);
        float rstd = rsqrtf(sq * (1.f / 256.f) - mu * mu + 1e-5f);
#pragma unroll
        for (int q = 0; q < 4; ++q) {
            uint2 u;
            u.x = pk_bf16((v[q].x - mu) * rstd * lw4[q].x + lb4[q].x,
                          (v[q].y - mu) * rstd * lw4[q].y + lb4[q].y);
            u.y = pk_bf16((v[q].z - mu) * rstd * lw4[q].z + lb4[q].z,
                          (v[q].w - mu) * rstd * lw4[q].w + lb4[q].w);
            *(uint2*)(xs + r * 266 + q * 64 + l16 * 4) = u;
        }
    }
    __syncthreads();   // covers b12/mkl too

    // MFMA: wave w -> rows [w*16,w*16+16) x 64 h; B-frags streamed from L2
    float4v zf4 = {0.f, 0.f, 0.f, 0.f};
    float4v acc[4]; acc[0] = zf4; acc[1] = zf4; acc[2] = zf4; acc[3] = zf4;
#pragma unroll
    for (int kk = 0; kk < 8; ++kk) {
        short8 af = *(const short8*)(xs + (w * 16 + l15) * 266 + kk * 32 + g * 8);
#pragma unroll
        for (int ht = 0; ht < 4; ++ht) {
            short8 bfr = *(const short8*)(w12F_in + ((size_t)(kk * 4 + ht) * 64 + lane) * 8);
            acc[ht] = mfma16(af, bfr, acc[ht]);
        }
    }
#pragma unroll
    for (int ht = 0; ht < 4; ++ht) {
        int h = ht * 16 + l15;
        float bias = b12[h];
        int rbase = w * 16 + g * 4;
        uint2 u;
        u.x = pk_bf16((acc[ht][0] + bias) * mkl[rbase + 0], (acc[ht][1] + bias) * mkl[rbase + 1]);
        u.y = pk_bf16((acc[ht][2] + bias) * mkl[rbase + 2], (acc[ht][3] + bias) * mkl[rbase + 3]);
        *(uint2*)(tr + h * 76 + rbase) = u;
    }
    __syncthreads();

    // gather 8-s runs; store into TILE-SWIZZLED global layout (16B units)
#pragma unroll
    for (int it = 0; it < 2; ++it) {
        int q = t + it * 256;
        int h = q >> 3, n_l = q & 7;
        unsigned short vv[8];
#pragma unroll
        for (int s_l = 0; s_l < 8; ++s_l)
            vv[s_l] = tr[h * 76 + s_l * 8 + n_l];
        uint4 u;
        u.x = (unsigned)vv[0] | ((unsigned)vv[1] << 16);
        u.y = (unsigned)vv[2] | ((unsigned)vv[3] << 16);
        u.z = (unsigned)vv[4] | ((unsigned)vv[5] << 16);
        u.w = (unsigned)vv[6] | ((unsigned)vv[7] << 16);
        int row = n_l * 32 + (h & 31);                         // tile-local row
        int dwcol = (s0 >> 1) ^ ((row & 7) << 2);              // baked swizzle
        unsigned short* dst = ((h < 32) ? aT : bT)
            + (size_t)(n0 >> 3) * 32768 + row * 128 + dwcol * 2;
        *(uint4*)dst = u;
    }
}

// =============== fused: GEMM1 + GEMM2 (K-split) + epilogue + wz ==============
// 256x256 (ic,je) tile = 8x8 (i,j) pairs per block; 512 threads; 128 KiB LDS.
__global__ __launch_bounds__(512, 2) void k2_fused(
    const unsigned short* __restrict__ aT, const unsigned short* __restrict__ bT,
    const unsigned short* __restrict__ wobF, const unsigned short* __restrict__ wzF,
    const float* __restrict__ b_out, const float* __restrict__ normw,
    const float* __restrict__ ln_ow, const float* __restrict__ ln_ob,
    const float* __restrict__ bz, float* __restrict__ out)
{
    __shared__ char smem[131072];
    unsigned* s32 = (unsigned*)smem;                        // A dw[0,16384) B dw[16384,32768)
    unsigned* oL = (unsigned*)smem;                         // 64 pairs x 512 dw, swizzled
    float* zA = (float*)smem;                               // [64][132] f32 (kh=0)
    float* zB = (float*)(smem + 33792);                     // [64][132] f32 (kh=1)
    unsigned short* lnL = (unsigned short*)(smem + 67584);  // [64][136] bf16

    int t = threadIdx.x;
    int w = t >> 6, lane = t & 63;
    int g = lane >> 4, l15 = lane & 15;
    int bj = blockIdx.x, bi = blockIdx.y;
    int wn = w & 1, wm = w >> 1;

    // ---------------- stage A,B: pure linear copy (global pre-swizzled) -------
    {
        const uint4* Agv = (const uint4*)(aT + (size_t)bi * 32768);
        const uint4* Bgv = (const uint4*)(bT + (size_t)bj * 32768);
#pragma unroll
        for (int it = 0; it < 8; ++it) {
            int q = t + it * 512;
            *(uint4*)(s32 + q * 4) = Agv[q];
            *(uint4*)(s32 + 16384 + q * 4) = Bgv[q];
        }
    }
    __syncthreads();

    // ---------------- GEMM1: 64(ic) x 128(je) per wave ------------------------
    float4v zf4 = {0.f, 0.f, 0.f, 0.f};
    float4v acc[4][8];
#pragma unroll
    for (int fm = 0; fm < 4; ++fm)
#pragma unroll
        for (int fn = 0; fn < 8; ++fn) acc[fm][fn] = zf4;

    {
        int sw = (l15 & 7) << 2;
#pragma unroll
        for (int kk = 0; kk < 4; ++kk) {
            int col = (kk * 16 + g * 4) ^ sw;
            short8 af[4], bf[8];
#pragma unroll
            for (int fm = 0; fm < 4; ++fm) {
                int row = wm * 64 + fm * 16 + l15;
                af[fm] = *(const short8*)((const char*)(s32 + row * 64 + col));
            }
#pragma unroll
            for (int fn = 0; fn < 8; ++fn) {
                int row = wn * 128 + fn * 16 + l15;
                bf[fn] = *(const short8*)((const char*)(s32 + 16384 + row * 64 + col));
            }
#pragma unroll
            for (int fm = 0; fm < 4; ++fm)
#pragma unroll
                for (int fn = 0; fn < 8; ++fn)   // swapped: D reg-dim = je, l15-dim = ic
                    acc[fm][fn] = mfma16(bf[fn], af[fm], acc[fm][fn]);
        }
    }
    __syncthreads();   // staging dead; region becomes oL

    // ---- pack outer -> LDS bf16; sigma(pair,off) = off ^ (((pair&7)^(off>>6))<<2)
#pragma unroll
    for (int fm = 0; fm < 4; ++fm) {
#pragma unroll
        for (int fn = 0; fn < 8; ++fn) {
            int pair = (wm * 2 + (fm >> 1)) * 8 + wn * 4 + (fn >> 1);
            int c = (fm & 1) * 16 + l15;
            int o = (fn & 1) * 8 + 2 * g;
            int off = c * 16 + o;
            int dw = pair * 512 + (off ^ ((((pair & 7) ^ (off >> 6)) & 7) << 2));
            float4v a4 = acc[fm][fn];
            uint2 u;
            u.x = pk_bf16(a4[0], a4[1]);
            u.y = pk_bf16(a4[2], a4[3]);
            *(uint2*)(oL + dw) = u;
        }
    }
    __syncthreads();

    // ------- GEMM2 (32x32x16, K-split): wave = all 64 pairs x 32p x 512k ------
    {
        int pw = w >> 1, kh = w & 1;
        int l31 = lane & 31, h2 = lane >> 5;
        float16v accA = {0.f};
        float16v accB = {0.f};
        const unsigned short* wbase = wobF + (size_t)w * 16384;
#pragma unroll 8
        for (int k16 = 0; k16 < 32; ++k16) {
            int kg = kh * 32 + k16;
            int off = kg * 8 + h2 * 4;
            int dws = off ^ ((((l31 & 7) ^ (off >> 6)) & 7) << 2);
            short8 b2 = *(const short8*)(wbase + (size_t)(k16 * 64 + lane) * 8);
            short8 aA = *(const short8*)(oL + l31 * 512 + dws);
            short8 aB = *(const short8*)(oL + (32 + l31) * 512 + dws);
            accA = mfma32(aA, b2, accA);
            accB = mfma32(aB, b2, accB);
        }
        __syncthreads();   // all oL reads done; region becomes zA/zB
        float* zdst = kh ? zB : zA;
#pragma unroll
        for (int reg = 0; reg < 16; ++reg) {
            int pr = (reg & 3) + 8 * (reg >> 2) + 4 * h2;
            zdst[pr * 132 + pw * 32 + l31] = accA[reg];
            zdst[(32 + pr) * 132 + pw * 32 + l31] = accB[reg];
        }
    }
    __syncthreads();

    // ---------------- epilogue: +b_out, /(eps+norm), gelu, LN(128) ------------
    {
        const float4 loA = *(const float4*)(ln_ow + l15 * 8);
        const float4 loB = *(const float4*)(ln_ow + l15 * 8 + 4);
        const float4 lbA = *(const float4*)(ln_ob + l15 * 8);
        const float4 lbB = *(const float4*)(ln_ob + l15 * 8 + 4);
        const float4 boA = *(const float4*)(b_out + l15 * 8);
        const float4 boB = *(const float4*)(b_out + l15 * 8 + 4);
        float lw8[8] = {loA.x, loA.y, loA.z, loA.w, loB.x, loB.y, loB.z, loB.w};
        float lb8[8] = {lbA.x, lbA.y, lbA.z, lbA.w, lbB.x, lbB.y, lbB.z, lbB.w};
        float bo8[8] = {boA.x, boA.y, boA.z, boA.w, boB.x, boB.y, boB.z, boB.w};
#pragma unroll
        for (int it = 0; it < 2; ++it) {
            int pair = w * 8 + it * 4 + g;
            int iG = bi * 8 + (pair >> 3), jG = bj * 8 + (pair & 7);
            float inv = 1.0f / (EPSC + normw[iG * 256 + jG]);
            float4v zA0 = *(const float4v*)(zA + pair * 132 + l15 * 8);
            float4v zA1 = *(const float4v*)(zA + pair * 132 + l15 * 8 + 4);
            float4v zB0 = *(const float4v*)(zB + pair * 132 + l15 * 8);
            float4v zB1 = *(const float4v*)(zB + pair * 132 + l15 * 8 + 4);
            float vals[8];
            float sum = 0.f, sq = 0.f;
#pragma unroll
            for (int e2 = 0; e2 < 8; ++e2) {
                float v = ((e2 < 4) ? (zA0[e2] + zB0[e2]) : (zA1[e2 - 4] + zB1[e2 - 4])) + bo8[e2];
                v *= inv;
                v = 0.5f * v * (1.0f + erff(v * 0.70710678118654752f));
                vals[e2] = v; sum += v; sq += v * v;
            }
#pragma unroll
            for (int mm = 1; mm <= 8; mm <<= 1) {
                sum += __shfl_xor(sum, mm);
                sq  += __shfl_xor(sq, mm);
            }
            float mu = sum * (1.0f / 128.0f);
            float rstd = rsqrtf(sq * (1.0f / 128.0f) - mu * mu + 1e-5f);
            uint4 upk;
            upk.x = pk_bf16((vals[0] - mu) * rstd * lw8[0] + lb8[0],
                            (vals[1] - mu) * rstd * lw8[1] + lb8[1]);
            upk.y = pk_bf16((vals[2] - mu) * rstd * lw8[2] + lb8[2],
                            (vals[3] - mu) * rstd * lw8[3] + lb8[3]);
            upk.z = pk_bf16((vals[4] - mu) * rstd * lw8[4] + lb8[4],
                            (vals[5] - mu) * rstd * lw8[5] + lb8[5]);
            upk.w = pk_bf16((vals[6] - mu) * rstd * lw8[6] + lb8[6],
                            (vals[7] - mu) * rstd * lw8[7] + lb8[7]);
            *(uint4*)(lnL + pair * 136 + l15 * 8) = upk;
        }
    }
    __syncthreads();

    // ---------------- wz matmul + bz, store; q-slice 16 per wave --------------
    {
        float4v acc3[4]; acc3[0] = zf4; acc3[1] = zf4; acc3[2] = zf4; acc3[3] = zf4;
#pragma unroll
        for (int kk = 0; kk < 4; ++kk) {
            short8 bfw = *(const short8*)(wzF + ((size_t)(w * 4 + kk) * 64 + lane) * 8);
#pragma unroll
            for (int fr = 0; fr < 4; ++fr) {
                short8 af3 = *(const short8*)(lnL + (fr * 16 + l15) * 136 + kk * 32 + g * 8);
                acc3[fr] = mfma16(af3, bfw, acc3[fr]);
            }
        }
        float bzq = bz[w * 16 + l15];
#pragma unroll
        for (int fr = 0; fr < 4; ++fr) {
#pragma unroll
            for (int r = 0; r < 4; ++r) {
                int pair = fr * 16 + g * 4 + r;
                int row = (bi * 8 + (pair >> 3)) * 256 + bj * 8 + (pair & 7);
                out[(size_t)row * 128 + w * 16 + l15] = acc3[fr][r] + bzq;
            }
        }
    }
}

extern "C" void kernel_launch(void* const* d_in, const int* in_sizes, int n_in,
                              void* d_out, int out_size, void* d_ws, size_t ws_size,
                              hipStream_t stream) {
    const float* m      = (const float*)d_in[0];
    const float* mask   = (const float*)d_in[1];
    const float* ln_w   = (const float*)d_in[2];
    const float* ln_b   = (const float*)d_in[3];
    const float* w1     = (const float*)d_in[4];
    const float* b1     = (const float*)d_in[5];
    const float* w2     = (const float*)d_in[6];
    const float* b2     = (const float*)d_in[7];
    const float* w_out  = (const float*)d_in[8];
    const float* b_out  = (const float*)d_in[9];
    const float* ln_ow  = (const float*)d_in[10];
    const float* ln_ob  = (const float*)d_in[11];
    const float* wz     = (const float*)d_in[12];
    const float* bz     = (const float*)d_in[13];
    float* out = (float*)d_out;
    char*  ws  = (char*)d_ws;

    float* normw          = (float*)(ws + OFF_NORM);
    unsigned short* aTb   = (unsigned short*)(ws + OFF_AT);
    unsigned short* bTb   = (unsigned short*)(ws + OFF_BT);
    unsigned short* wobF  = (unsigned short*)(ws + OFF_WOF);
    unsigned short* wzF   = (unsigned short*)(ws + OFF_WZF);
    unsigned short* w12F  = (unsigned short*)(ws + OFF_W12);

    // w12F must be ready before k_pre's LN/proj blocks read it (cross-block
    // ordering within one dispatch is undefined) -> tiny dedicated launch.
    {
        struct L {
            static __global__ void __launch_bounds__(256) cvt12(
                const float* __restrict__ w1, const float* __restrict__ w2,
                unsigned short* __restrict__ w12F) {
                int q = blockIdx.x * 256 + threadIdx.x;   // 16384
                int j = q & 7, lane = (q >> 3) & 63, ht = (q >> 9) & 3, kk = q >> 11;
                int h = ht * 16 + (lane & 15);
                int d = kk * 32 + (lane >> 4) * 8 + j;
                w12F[q] = f2bf(h < 32 ? w1[h * 256 + d] : w2[(h - 32) * 256 + d]);
            }
        };
        L::cvt12<<<dim3(64), dim3(256), 0, stream>>>(w1, w2, w12F);
    }
    k_pre<<<dim3(1408), dim3(256), 0, stream>>>(m, mask, ln_w, ln_b, w1, b1, w2, b2,
                                                w_out, wz, aTb, bTb, wobF, wzF,
                                                w12F, w12F, normw);
    k2_fused<<<dim3(32, 32), dim3(512), 0, stream>>>(aTb, bTb, wobF, wzF, b_out, normw,
                                                     ln_ow, ln_ob, bz, out);
}